// Round 4
// baseline (20760.652 us; speedup 1.0000x reference)
//
#include <hip/hip_runtime.h>
#include <hip/hip_bf16.h>

// Problem constants
#define Bx 32
#define Nx 512
#define Dx 512
#define Hx 8
#define DKx 64
#define FFx 2048
#define TOK (Bx * Nx)          // 16384 tokens
#define NBC 8                  // batches per attention chunk
#define EPSx 1e-5f

// ---------------------------------------------------------------------------
// Inputs may be fp32 or bf16; detected at runtime on-device. Kernels reading
// INPUT tensors get two candidate pointers (pre-offset on host as float* and
// bf16*) plus the flag. ALL internal buffers fp32. Output fp32.
// ---------------------------------------------------------------------------
__device__ __forceinline__ float ldsel(const void* p32, const void* p16, size_t i, int f32) {
    return f32 ? ((const float*)p32)[i]
               : __bfloat162float(((const __hip_bfloat16*)p16)[i]);
}

// bf16 N(0,1) data: every halfword exponent < 0x86 (|v|<64).
// fp32 data: low halfwords are mantissa noise -> ~47% exponents >= 0x86.
__global__ void detect_kernel(const void* __restrict__ x, int* __restrict__ flag)
{
    if (threadIdx.x == 0 && blockIdx.x == 0) {
        const unsigned short* u = (const unsigned short*)x;
        int hits = 0;
        for (int i = 0; i < 256; ++i) {
            int e = (u[i] >> 7) & 0xFF;
            if (e >= 0x86) ++hits;
        }
        *flag = (hits > 8) ? 1 : 0;
    }
}

// ---------------------------------------------------------------------------
__global__ __launch_bounds__(256) void embed_kernel(
    const void* __restrict__ x, const void* __restrict__ We,
    const void* __restrict__ be, float* __restrict__ h, const int* __restrict__ dtp)
{
    const int f32 = *dtp;
    size_t idx = (size_t)blockIdx.x * 256 + threadIdx.x;   // 0 .. TOK*Dx
    int d = idx & (Dx - 1);
    size_t t = idx >> 9;
    float v = ldsel(x, x, t * 2, f32)     * ldsel(We, We, d * 2, f32) +
              ldsel(x, x, t * 2 + 1, f32) * ldsel(We, We, d * 2 + 1, f32) +
              ldsel(be, be, d, f32);
    h[idx] = v;
}

// ---------------------------------------------------------------------------
// Generic tiled GEMM: out[m,n] = sum_k A[m,k] * B(n,k)  (+ epilogue)
// A is always fp32 internal. W/bias are INPUTS (dual dtype).
// BL: 0 W[n*K+k] ; 1 W[(n>>6)*K*64 + k*64 + (n&63)] (QKV [H,D,DK]) ;
//     2 W[k*N+n] (Wo flattened [H*DK, D])
// OL: 0 row-major fp32 ; 1 scatter to [H, NB, N, DK] fp32 (NB = M>>9)
// EPI: 0 plain ; 1 +bias,relu ; 2 +bias(opt)+resid
// ---------------------------------------------------------------------------
template <int BL, int OL, int EPI>
__global__ __launch_bounds__(256) void gemm_kernel(
    const float* __restrict__ A,
    const void* __restrict__ W32, const void* __restrict__ W16,
    const void* __restrict__ bias32, const void* __restrict__ bias16,
    const float* __restrict__ resid,
    float* __restrict__ outp, int M, int N, int K, const int* __restrict__ dtp)
{
    const int f32 = *dtp;
    __shared__ float As[16][65];
    __shared__ float Bs[16][65];
    const int tid = threadIdx.x;
    const int bm = blockIdx.y * 64;
    const int bn = blockIdx.x * 64;
    const int tx = tid & 15, ty = tid >> 4;
    float acc[4][4] = {};

    for (int k0 = 0; k0 < K; k0 += 16) {
        #pragma unroll
        for (int i = 0; i < 4; ++i) {
            int idx = tid + i * 256;           // 0..1023
            int k = idx & 15, m = idx >> 4;
            As[k][m] = A[(size_t)(bm + m) * K + (k0 + k)];
        }
        #pragma unroll
        for (int i = 0; i < 4; ++i) {
            int idx = tid + i * 256;
            int n, k;
            if constexpr (BL == 0) { k = idx & 15; n = idx >> 4; }
            else                   { n = idx & 63; k = idx >> 6; }
            int gn = bn + n, gk = k0 + k;
            size_t widx;
            if constexpr (BL == 0)      widx = (size_t)gn * K + gk;
            else if constexpr (BL == 1) widx = (size_t)(gn >> 6) * ((size_t)K * 64) + (size_t)gk * 64 + (gn & 63);
            else                        widx = (size_t)gk * N + gn;
            Bs[k][n] = ldsel(W32, W16, widx, f32);
        }
        __syncthreads();
        #pragma unroll
        for (int kk = 0; kk < 16; ++kk) {
            float a[4], b[4];
            #pragma unroll
            for (int i = 0; i < 4; ++i) a[i] = As[kk][ty * 4 + i];
            #pragma unroll
            for (int j = 0; j < 4; ++j) b[j] = Bs[kk][tx * 4 + j];
            #pragma unroll
            for (int i = 0; i < 4; ++i)
                #pragma unroll
                for (int j = 0; j < 4; ++j) acc[i][j] += a[i] * b[j];
        }
        __syncthreads();
    }

    const int nb = M >> 9;   // batches in this GEMM (for OL==1 scatter)
    #pragma unroll
    for (int i = 0; i < 4; ++i) {
        int m = bm + ty * 4 + i;
        #pragma unroll
        for (int j = 0; j < 4; ++j) {
            int n = bn + tx * 4 + j;
            float v = acc[i][j];
            if constexpr (EPI == 1) { v += ldsel(bias32, bias16, n, f32); v = fmaxf(v, 0.f); }
            if constexpr (EPI == 2) {
                if (bias32) v += ldsel(bias32, bias16, n, f32);
                v += resid[(size_t)m * N + n];
            }
            if constexpr (OL == 0) {
                outp[(size_t)m * N + n] = v;
            } else {
                int head = n >> 6, kk2 = n & 63;
                int b_ = m >> 9, q = m & 511;   // chunk-local batch
                size_t oidx = ((((size_t)head * nb + b_) * Nx + q) * DKx) + kk2;
                outp[oidx] = v;
            }
        }
    }
}

// ---------------------------------------------------------------------------
// Attention: one wave per (head, batch_local, q-row). Q,K,V fp32 [H,NBC,N,DK].
// heads out: [tokens, H*DK] fp32 (global token = (b0 + b_local)*N + q).
// ---------------------------------------------------------------------------
__global__ __launch_bounds__(256) void attn_kernel(
    const float* __restrict__ Q, const float* __restrict__ K,
    const float* __restrict__ V, float* __restrict__ heads, int b0)
{
    __shared__ float sc[4][Nx];
    __shared__ float qs[4][DKx];
    const int lane = threadIdx.x & 63;
    const int wv = threadIdx.x >> 6;
    const int w = blockIdx.x * 4 + wv;        // 0 .. H*NBC*N
    const int q = w & (Nx - 1);
    const int hb = w >> 9;                    // h_*NBC + b_local
    const size_t base = (size_t)hb * (Nx * DKx);

    qs[wv][lane] = Q[base + (size_t)q * DKx + lane];
    __syncthreads();

    float s[8];
    #pragma unroll
    for (int c = 0; c < 8; ++c) {
        int n = c * 64 + lane;
        const float* kp = K + base + (size_t)n * DKx;
        float d = 0.f;
        #pragma unroll
        for (int k = 0; k < DKx; ++k) d += qs[wv][k] * kp[k];
        s[c] = d * 0.125f;  // 1/sqrt(64)
    }
    float m = s[0];
    #pragma unroll
    for (int c = 1; c < 8; ++c) m = fmaxf(m, s[c]);
    #pragma unroll
    for (int off = 32; off; off >>= 1) m = fmaxf(m, __shfl_xor(m, off, 64));
    float sum = 0.f;
    #pragma unroll
    for (int c = 0; c < 8; ++c) { s[c] = __expf(s[c] - m); sum += s[c]; }
    #pragma unroll
    for (int off = 32; off; off >>= 1) sum += __shfl_xor(sum, off, 64);
    float inv = 1.f / sum;
    #pragma unroll
    for (int c = 0; c < 8; ++c) sc[wv][c * 64 + lane] = s[c] * inv;
    __syncthreads();

    float acc = 0.f;
    for (int n = 0; n < Nx; ++n)
        acc += sc[wv][n] * V[base + (size_t)n * DKx + lane];

    int h_ = hb / NBC, b_ = hb % NBC;
    size_t tok = (size_t)(b0 + b_) * Nx + q;
    heads[tok * Dx + h_ * DKx + lane] = acc;
}

// ---------------------------------------------------------------------------
__global__ __launch_bounds__(256) void bn_stats(const float* __restrict__ t, float* __restrict__ stats)
{
    int r0 = blockIdx.x * 64;
    int c = threadIdx.x;   // 0..255
    float s0 = 0, q0 = 0, s1 = 0, q1 = 0;
    for (int r = 0; r < 64; ++r) {
        const float* row = t + (size_t)(r0 + r) * Dx;
        float v0 = row[c], v1 = row[c + 256];
        s0 += v0; q0 += v0 * v0; s1 += v1; q1 += v1 * v1;
    }
    atomicAdd(&stats[c], s0);
    atomicAdd(&stats[c + 256], s1);
    atomicAdd(&stats[Dx + c], q0);
    atomicAdd(&stats[Dx + c + 256], q1);
}

__global__ __launch_bounds__(256) void bn_norm(
    const float* __restrict__ t, const float* __restrict__ stats,
    const void* __restrict__ g32, const void* __restrict__ g16,
    const void* __restrict__ b32, const void* __restrict__ b16,
    float* __restrict__ h, const int* __restrict__ dtp)
{
    const int f32 = *dtp;
    size_t idx = (size_t)blockIdx.x * 256 + threadIdx.x;  // TOK*Dx
    int c = idx & (Dx - 1);
    const float invM = 1.f / (float)TOK;
    float mu = stats[c] * invM;
    float var = stats[Dx + c] * invM - mu * mu;
    float v = (t[idx] - mu) * rsqrtf(var + EPSx) * ldsel(g32, g16, c, f32) + ldsel(b32, b16, c, f32);
    h[idx] = v;
}

// ---------------------------------------------------------------------------
// Outputs: FP32
// ---------------------------------------------------------------------------
__global__ __launch_bounds__(256) void out_h_kernel(const float* __restrict__ h, float* __restrict__ out)
{
    size_t idx = (size_t)blockIdx.x * 256 + threadIdx.x;
    out[idx] = h[idx];
}

__global__ __launch_bounds__(512) void out_mean_kernel(const float* __restrict__ h, float* __restrict__ out2)
{
    int b = blockIdx.x;       // 0..31
    int d = threadIdx.x;      // 0..511
    float s = 0.f;
    for (int n = 0; n < Nx; ++n) s += h[((size_t)b * Nx + n) * Dx + d];
    out2[b * Dx + d] = s * (1.f / (float)Nx);
}

// ---------------------------------------------------------------------------
extern "C" void kernel_launch(void* const* d_in, const int* in_sizes, int n_in,
                              void* d_out, int out_size, void* d_ws, size_t ws_size,
                              hipStream_t stream)
{
    const void* x   = d_in[0];
    const void* We  = d_in[1];
    const void* be  = d_in[2];
    const void* Wq  = d_in[3];
    const void* Wk  = d_in[4];
    const void* Wv  = d_in[5];
    const void* Wo  = d_in[6];
    const void* g1  = d_in[7];
    const void* b1  = d_in[8];
    const void* W1  = d_in[9];
    const void* bb1 = d_in[10];
    const void* W2  = d_in[11];
    const void* bb2 = d_in[12];
    const void* g2  = d_in[13];
    const void* b2  = d_in[14];

    const size_t szWqkv = (size_t)Hx * Dx * DKx;
    const size_t szWo   = (size_t)Hx * DKx * Dx;
    const size_t szW1   = (size_t)FFx * Dx;
    const size_t szW2   = (size_t)Dx * FFx;

    // workspace layout (all fp32): total ~126 MB
    const size_t CH = (size_t)Hx * NBC * Nx * DKx;   // 2,097,152 floats (8 MB)
    float* h     = (float*)d_ws;                     // TOK*Dx
    float* t     = h + (size_t)TOK * Dx;             // TOK*Dx
    float* heads = t + (size_t)TOK * Dx;             // TOK*Dx
    float* Qb    = heads + (size_t)TOK * Dx;         // CH
    float* Kb    = Qb + CH;                          // CH
    float* Vb    = Kb + CH;                          // CH
    float* stats = Vb + CH;                          // 1024
    int*   dtp   = (int*)(stats + 2 * Dx);
    float* ffbuf = Qb;  // [2048, 2048] f32 = 16 MB, reuses dead QKV region (24 MB)

    auto p32 = [](const void* p, size_t e) { return (const void*)((const float*)p + e); };
    auto p16 = [](const void* p, size_t e) { return (const void*)((const __hip_bfloat16*)p + e); };

    detect_kernel<<<1, 64, 0, stream>>>(x, dtp);
    embed_kernel<<<TOK * Dx / 256, 256, 0, stream>>>(x, We, be, h, dtp);

    const int chTok = NBC * Nx;                       // 4096 tokens per attn chunk
    const dim3 gQKV(Dx / 64, chTok / 64);             // (8, 64)
    const dim3 gWo(Dx / 64, TOK / 64);                // (8, 256)
    for (int l = 0; l < 3; ++l) {
        const size_t eW = (size_t)l * szWqkv, eO = (size_t)l * szWo;
        const size_t e1 = (size_t)l * szW1,  e2 = (size_t)l * szW2;
        const size_t eD = (size_t)l * Dx,    eF = (size_t)l * FFx;

        // attention in 4 chunks of NBC batches (QKV fp32, chunk-resident)
        for (int ch = 0; ch < 4; ++ch) {
            const float* hc = h + (size_t)ch * chTok * Dx;
            gemm_kernel<1, 1, 0><<<gQKV, 256, 0, stream>>>(
                hc, p32(Wq, eW), p16(Wq, eW), nullptr, nullptr, nullptr, Qb, chTok, Dx, Dx, dtp);
            gemm_kernel<1, 1, 0><<<gQKV, 256, 0, stream>>>(
                hc, p32(Wk, eW), p16(Wk, eW), nullptr, nullptr, nullptr, Kb, chTok, Dx, Dx, dtp);
            gemm_kernel<1, 1, 0><<<gQKV, 256, 0, stream>>>(
                hc, p32(Wv, eW), p16(Wv, eW), nullptr, nullptr, nullptr, Vb, chTok, Dx, Dx, dtp);
            attn_kernel<<<Hx * NBC * Nx / 4, 256, 0, stream>>>(Qb, Kb, Vb, heads, ch * NBC);
        }

        // output projection + residual: t = h + heads @ Wo_flat
        gemm_kernel<2, 0, 2><<<gWo, 256, 0, stream>>>(
            heads, p32(Wo, eO), p16(Wo, eO), nullptr, nullptr, h, t, TOK, Dx, Dx, dtp);

        hipMemsetAsync(stats, 0, 2 * Dx * sizeof(float), stream);
        bn_stats<<<256, 256, 0, stream>>>(t, stats);
        bn_norm<<<TOK * Dx / 256, 256, 0, stream>>>(
            t, stats, p32(g1, eD), p16(g1, eD), p32(b1, eD), p16(b1, eD), h, dtp);

        // FF in 8 chunks of 2048 tokens (ffbuf fp32 [2048, 2048])
        for (int ch = 0; ch < 8; ++ch) {
            float* hc = h + (size_t)ch * 2048 * Dx;
            float* tc = t + (size_t)ch * 2048 * Dx;
            gemm_kernel<0, 0, 1><<<dim3(FFx / 64, 2048 / 64), 256, 0, stream>>>(
                hc, p32(W1, e1), p16(W1, e1), p32(bb1, eF), p16(bb1, eF), nullptr, ffbuf, 2048, FFx, Dx, dtp);
            gemm_kernel<0, 0, 2><<<dim3(Dx / 64, 2048 / 64), 256, 0, stream>>>(
                ffbuf, p32(W2, e2), p16(W2, e2), p32(bb2, eD), p16(bb2, eD), hc, tc, 2048, Dx, FFx, dtp);
        }

        hipMemsetAsync(stats, 0, 2 * Dx * sizeof(float), stream);
        bn_stats<<<256, 256, 0, stream>>>(t, stats);
        bn_norm<<<TOK * Dx / 256, 256, 0, stream>>>(
            t, stats, p32(g2, eD), p16(g2, eD), p32(b2, eD), p16(b2, eD), h, dtp);
    }

    out_h_kernel<<<TOK * Dx / 256, 256, 0, stream>>>(h, (float*)d_out);
    out_mean_kernel<<<Bx, Dx, 0, stream>>>(h, (float*)d_out + (size_t)TOK * Dx);
}

// Round 5
// 12941.731 us; speedup vs baseline: 1.6042x; 1.6042x over previous
//
#include <hip/hip_runtime.h>
#include <hip/hip_bf16.h>

// Problem constants
#define Bx 32
#define Nx 512
#define Dx 512
#define Hx 8
#define DKx 64
#define FFx 2048
#define TOK (Bx * Nx)          // 16384 tokens
#define NBC 8                  // batches per attention chunk
#define EPSx 1e-5f

// ---------------------------------------------------------------------------
// Inputs may be fp32 or bf16; detected at runtime on-device. Kernels reading
// INPUT tensors get two candidate pointers (pre-offset on host as float* and
// bf16*) plus the flag. ALL internal buffers fp32. Output fp32.
// ---------------------------------------------------------------------------
__device__ __forceinline__ float ldsel(const void* p32, const void* p16, size_t i, int f32) {
    return f32 ? ((const float*)p32)[i]
               : __bfloat162float(((const __hip_bfloat16*)p16)[i]);
}

__global__ void detect_kernel(const void* __restrict__ x, int* __restrict__ flag)
{
    if (threadIdx.x == 0 && blockIdx.x == 0) {
        const unsigned short* u = (const unsigned short*)x;
        int hits = 0;
        for (int i = 0; i < 256; ++i) {
            int e = (u[i] >> 7) & 0xFF;
            if (e >= 0x86) ++hits;
        }
        *flag = (hits > 8) ? 1 : 0;
    }
}

// ---------------------------------------------------------------------------
__global__ __launch_bounds__(256) void embed_kernel(
    const void* __restrict__ x, const void* __restrict__ We,
    const void* __restrict__ be, float* __restrict__ h, const int* __restrict__ dtp)
{
    const int f32 = *dtp;
    size_t idx = (size_t)blockIdx.x * 256 + threadIdx.x;   // 0 .. TOK*Dx
    int d = idx & (Dx - 1);
    size_t t = idx >> 9;
    float v = ldsel(x, x, t * 2, f32)     * ldsel(We, We, d * 2, f32) +
              ldsel(x, x, t * 2 + 1, f32) * ldsel(We, We, d * 2 + 1, f32) +
              ldsel(be, be, d, f32);
    h[idx] = v;
}

// ---------------------------------------------------------------------------
// Generic tiled GEMM: out[m,n] = sum_k A[m,k] * B(n,k)  (+ epilogue)
// BL: 0 W[n*K+k] ; 1 W[(n>>6)*K*64 + k*64 + (n&63)] (QKV [H,D,DK]) ;
//     2 W[k*N+n] (Wo flattened [H*DK, D])
// OL: 0 row-major fp32 ; 1 scatter to [H, NB, N, DK] fp32 (NB = M>>9)
// EPI: 0 plain ; 1 +bias,relu ; 2 +bias(opt)+resid
// ---------------------------------------------------------------------------
template <int BL, int OL, int EPI>
__global__ __launch_bounds__(256) void gemm_kernel(
    const float* __restrict__ A,
    const void* __restrict__ W32, const void* __restrict__ W16,
    const void* __restrict__ bias32, const void* __restrict__ bias16,
    const float* __restrict__ resid,
    float* __restrict__ outp, int M, int N, int K, const int* __restrict__ dtp)
{
    const int f32 = *dtp;
    __shared__ float As[16][65];
    __shared__ float Bs[16][65];
    const int tid = threadIdx.x;
    const int bm = blockIdx.y * 64;
    const int bn = blockIdx.x * 64;
    const int tx = tid & 15, ty = tid >> 4;
    float acc[4][4] = {};

    for (int k0 = 0; k0 < K; k0 += 16) {
        #pragma unroll
        for (int i = 0; i < 4; ++i) {
            int idx = tid + i * 256;           // 0..1023
            int k = idx & 15, m = idx >> 4;
            As[k][m] = A[(size_t)(bm + m) * K + (k0 + k)];
        }
        #pragma unroll
        for (int i = 0; i < 4; ++i) {
            int idx = tid + i * 256;
            int n, k;
            if constexpr (BL == 0) { k = idx & 15; n = idx >> 4; }
            else                   { n = idx & 63; k = idx >> 6; }
            int gn = bn + n, gk = k0 + k;
            size_t widx;
            if constexpr (BL == 0)      widx = (size_t)gn * K + gk;
            else if constexpr (BL == 1) widx = (size_t)(gn >> 6) * ((size_t)K * 64) + (size_t)gk * 64 + (gn & 63);
            else                        widx = (size_t)gk * N + gn;
            Bs[k][n] = ldsel(W32, W16, widx, f32);
        }
        __syncthreads();
        #pragma unroll
        for (int kk = 0; kk < 16; ++kk) {
            float a[4], b[4];
            #pragma unroll
            for (int i = 0; i < 4; ++i) a[i] = As[kk][ty * 4 + i];
            #pragma unroll
            for (int j = 0; j < 4; ++j) b[j] = Bs[kk][tx * 4 + j];
            #pragma unroll
            for (int i = 0; i < 4; ++i)
                #pragma unroll
                for (int j = 0; j < 4; ++j) acc[i][j] += a[i] * b[j];
        }
        __syncthreads();
    }

    const int nb = M >> 9;   // batches in this GEMM (for OL==1 scatter)
    #pragma unroll
    for (int i = 0; i < 4; ++i) {
        int m = bm + ty * 4 + i;
        #pragma unroll
        for (int j = 0; j < 4; ++j) {
            int n = bn + tx * 4 + j;
            float v = acc[i][j];
            if constexpr (EPI == 1) { v += ldsel(bias32, bias16, n, f32); v = fmaxf(v, 0.f); }
            if constexpr (EPI == 2) {
                if (bias32) v += ldsel(bias32, bias16, n, f32);
                v += resid[(size_t)m * N + n];
            }
            if constexpr (OL == 0) {
                outp[(size_t)m * N + n] = v;
            } else {
                int head = n >> 6, kk2 = n & 63;
                int b_ = m >> 9, q = m & 511;   // chunk-local batch
                size_t oidx = ((((size_t)head * nb + b_) * Nx + q) * DKx) + kk2;
                outp[oidx] = v;
            }
        }
    }
}

// ---------------------------------------------------------------------------
// Flash-style attention: block = (hb, 64-q-row tile). Q,K,V fp32 [H,NBC,N,DK].
// LDS-staged tiles, online softmax (m/l/alpha per q-row), O in registers
// (4x4 microtile per thread). heads out: [tokens, H*DK] fp32.
// ---------------------------------------------------------------------------
__global__ __launch_bounds__(256) void attn_kernel(
    const float* __restrict__ Q, const float* __restrict__ K,
    const float* __restrict__ V, float* __restrict__ heads, int b0)
{
    __shared__ float Qs[64][65];
    __shared__ float Ks[64][65];
    __shared__ float Vs[64][65];
    __shared__ float Ss[64][65];
    __shared__ float ml[64], ll[64], al[64];

    const int tid = threadIdx.x;
    const int q0 = blockIdx.x * 64;          // q tile base
    const int hb = blockIdx.y;               // h*NBC + b_local
    const size_t base = (size_t)hb * (Nx * DKx);
    const int tx = tid & 15, ty = tid >> 4;

    // load Q tile (coalesced: consecutive tid -> consecutive dk)
    #pragma unroll
    for (int i = 0; i < 16; ++i) {
        int idx = tid + i * 256;             // 0..4095
        int r = idx >> 6, c = idx & 63;
        Qs[r][c] = Q[base + (size_t)(q0 + r) * DKx + c];
    }
    if (tid < 64) { ml[tid] = -INFINITY; ll[tid] = 0.f; }

    float acc[4][4] = {};                    // O[q=ty*4+i][dk=tx*4+j]

    for (int n0 = 0; n0 < Nx; n0 += 64) {
        __syncthreads();                     // protect Ks/Vs (prev PV reads)
        #pragma unroll
        for (int i = 0; i < 16; ++i) {
            int idx = tid + i * 256;
            int r = idx >> 6, c = idx & 63;
            Ks[r][c] = K[base + (size_t)(n0 + r) * DKx + c];
            Vs[r][c] = V[base + (size_t)(n0 + r) * DKx + c];
        }
        __syncthreads();

        // scores S[q][n] = 0.125 * sum_k Qs[q][k]*Ks[n][k]
        float s[4][4] = {};
        #pragma unroll
        for (int k = 0; k < DKx; ++k) {
            float a[4], b[4];
            #pragma unroll
            for (int i = 0; i < 4; ++i) a[i] = Qs[ty * 4 + i][k];
            #pragma unroll
            for (int j = 0; j < 4; ++j) b[j] = Ks[tx * 4 + j][k];
            #pragma unroll
            for (int i = 0; i < 4; ++i)
                #pragma unroll
                for (int j = 0; j < 4; ++j) s[i][j] += a[i] * b[j];
        }
        #pragma unroll
        for (int i = 0; i < 4; ++i)
            #pragma unroll
            for (int j = 0; j < 4; ++j) Ss[ty * 4 + i][tx * 4 + j] = s[i][j] * 0.125f;
        __syncthreads();

        // per-row online-softmax stats (threads 0..63, one q row each)
        if (tid < 64) {
            float rowmax = -INFINITY;
            #pragma unroll 8
            for (int n = 0; n < 64; ++n) rowmax = fmaxf(rowmax, Ss[tid][n]);
            float mold = ml[tid];
            float mnew = fmaxf(mold, rowmax);
            float alpha = __expf(mold - mnew);        // 0 if mold==-inf
            float sum = 0.f;
            #pragma unroll 8
            for (int n = 0; n < 64; ++n) {
                float p = __expf(Ss[tid][n] - mnew);
                Ss[tid][n] = p;
                sum += p;
            }
            ml[tid] = mnew;
            ll[tid] = ll[tid] * alpha + sum;
            al[tid] = alpha;
        }
        __syncthreads();

        // O = O*alpha + P @ Vs
        float aq[4];
        #pragma unroll
        for (int i = 0; i < 4; ++i) aq[i] = al[ty * 4 + i];
        #pragma unroll
        for (int i = 0; i < 4; ++i)
            #pragma unroll
            for (int j = 0; j < 4; ++j) acc[i][j] *= aq[i];
        #pragma unroll
        for (int n = 0; n < 64; ++n) {
            float a[4], b[4];
            #pragma unroll
            for (int i = 0; i < 4; ++i) a[i] = Ss[ty * 4 + i][n];
            #pragma unroll
            for (int j = 0; j < 4; ++j) b[j] = Vs[n][tx * 4 + j];
            #pragma unroll
            for (int i = 0; i < 4; ++i)
                #pragma unroll
                for (int j = 0; j < 4; ++j) acc[i][j] += a[i] * b[j];
        }
    }
    __syncthreads();

    // finalize: O /= l ; write heads[(b0+b)*N+q0+q][h*64+dk]
    const int h_ = hb / NBC, b_ = hb % NBC;
    #pragma unroll
    for (int i = 0; i < 4; ++i) {
        int q = ty * 4 + i;
        float invl = 1.f / ll[q];
        size_t tok = (size_t)(b0 + b_) * Nx + (q0 + q);
        #pragma unroll
        for (int j = 0; j < 4; ++j) {
            heads[tok * Dx + h_ * DKx + tx * 4 + j] = acc[i][j] * invl;
        }
    }
}

// ---------------------------------------------------------------------------
__global__ __launch_bounds__(256) void bn_stats(const float* __restrict__ t, float* __restrict__ stats)
{
    int r0 = blockIdx.x * 64;
    int c = threadIdx.x;   // 0..255
    float s0 = 0, q0 = 0, s1 = 0, q1 = 0;
    for (int r = 0; r < 64; ++r) {
        const float* row = t + (size_t)(r0 + r) * Dx;
        float v0 = row[c], v1 = row[c + 256];
        s0 += v0; q0 += v0 * v0; s1 += v1; q1 += v1 * v1;
    }
    atomicAdd(&stats[c], s0);
    atomicAdd(&stats[c + 256], s1);
    atomicAdd(&stats[Dx + c], q0);
    atomicAdd(&stats[Dx + c + 256], q1);
}

__global__ __launch_bounds__(256) void bn_norm(
    const float* __restrict__ t, const float* __restrict__ stats,
    const void* __restrict__ g32, const void* __restrict__ g16,
    const void* __restrict__ b32, const void* __restrict__ b16,
    float* __restrict__ h, const int* __restrict__ dtp)
{
    const int f32 = *dtp;
    size_t idx = (size_t)blockIdx.x * 256 + threadIdx.x;  // TOK*Dx
    int c = idx & (Dx - 1);
    const float invM = 1.f / (float)TOK;
    float mu = stats[c] * invM;
    float var = stats[Dx + c] * invM - mu * mu;
    float v = (t[idx] - mu) * rsqrtf(var + EPSx) * ldsel(g32, g16, c, f32) + ldsel(b32, b16, c, f32);
    h[idx] = v;
}

// ---------------------------------------------------------------------------
__global__ __launch_bounds__(256) void out_h_kernel(const float* __restrict__ h, float* __restrict__ out)
{
    size_t idx = (size_t)blockIdx.x * 256 + threadIdx.x;
    out[idx] = h[idx];
}

__global__ __launch_bounds__(512) void out_mean_kernel(const float* __restrict__ h, float* __restrict__ out2)
{
    int b = blockIdx.x;       // 0..31
    int d = threadIdx.x;      // 0..511
    float s = 0.f;
    for (int n = 0; n < Nx; ++n) s += h[((size_t)b * Nx + n) * Dx + d];
    out2[b * Dx + d] = s * (1.f / (float)Nx);
}

// ---------------------------------------------------------------------------
extern "C" void kernel_launch(void* const* d_in, const int* in_sizes, int n_in,
                              void* d_out, int out_size, void* d_ws, size_t ws_size,
                              hipStream_t stream)
{
    const void* x   = d_in[0];
    const void* We  = d_in[1];
    const void* be  = d_in[2];
    const void* Wq  = d_in[3];
    const void* Wk  = d_in[4];
    const void* Wv  = d_in[5];
    const void* Wo  = d_in[6];
    const void* g1  = d_in[7];
    const void* b1  = d_in[8];
    const void* W1  = d_in[9];
    const void* bb1 = d_in[10];
    const void* W2  = d_in[11];
    const void* bb2 = d_in[12];
    const void* g2  = d_in[13];
    const void* b2  = d_in[14];

    const size_t szWqkv = (size_t)Hx * Dx * DKx;
    const size_t szWo   = (size_t)Hx * DKx * Dx;
    const size_t szW1   = (size_t)FFx * Dx;
    const size_t szW2   = (size_t)Dx * FFx;

    // workspace layout (all fp32): total ~126 MB
    const size_t CH = (size_t)Hx * NBC * Nx * DKx;   // 2,097,152 floats (8 MB)
    float* h     = (float*)d_ws;                     // TOK*Dx
    float* t     = h + (size_t)TOK * Dx;             // TOK*Dx
    float* heads = t + (size_t)TOK * Dx;             // TOK*Dx
    float* Qb    = heads + (size_t)TOK * Dx;         // CH
    float* Kb    = Qb + CH;                          // CH
    float* Vb    = Kb + CH;                          // CH
    float* stats = Vb + CH;                          // 1024
    int*   dtp   = (int*)(stats + 2 * Dx);
    float* ffbuf = Qb;  // [2048, 2048] f32 = 16 MB, reuses dead QKV region (24 MB)

    auto p32 = [](const void* p, size_t e) { return (const void*)((const float*)p + e); };
    auto p16 = [](const void* p, size_t e) { return (const void*)((const __hip_bfloat16*)p + e); };

    detect_kernel<<<1, 64, 0, stream>>>(x, dtp);
    embed_kernel<<<TOK * Dx / 256, 256, 0, stream>>>(x, We, be, h, dtp);

    const int chTok = NBC * Nx;                       // 4096 tokens per attn chunk
    const dim3 gQKV(Dx / 64, chTok / 64);             // (8, 64)
    const dim3 gWo(Dx / 64, TOK / 64);                // (8, 256)
    const dim3 gAttn(Nx / 64, Hx * NBC);              // (8, 64)
    for (int l = 0; l < 3; ++l) {
        const size_t eW = (size_t)l * szWqkv, eO = (size_t)l * szWo;
        const size_t e1 = (size_t)l * szW1,  e2 = (size_t)l * szW2;
        const size_t eD = (size_t)l * Dx,    eF = (size_t)l * FFx;

        // attention in 4 chunks of NBC batches (QKV fp32, chunk-resident)
        for (int ch = 0; ch < 4; ++ch) {
            const float* hc = h + (size_t)ch * chTok * Dx;
            gemm_kernel<1, 1, 0><<<gQKV, 256, 0, stream>>>(
                hc, p32(Wq, eW), p16(Wq, eW), nullptr, nullptr, nullptr, Qb, chTok, Dx, Dx, dtp);
            gemm_kernel<1, 1, 0><<<gQKV, 256, 0, stream>>>(
                hc, p32(Wk, eW), p16(Wk, eW), nullptr, nullptr, nullptr, Kb, chTok, Dx, Dx, dtp);
            gemm_kernel<1, 1, 0><<<gQKV, 256, 0, stream>>>(
                hc, p32(Wv, eW), p16(Wv, eW), nullptr, nullptr, nullptr, Vb, chTok, Dx, Dx, dtp);
            attn_kernel<<<gAttn, 256, 0, stream>>>(Qb, Kb, Vb, heads, ch * NBC);
        }

        // output projection + residual: t = h + heads @ Wo_flat
        gemm_kernel<2, 0, 2><<<gWo, 256, 0, stream>>>(
            heads, p32(Wo, eO), p16(Wo, eO), nullptr, nullptr, h, t, TOK, Dx, Dx, dtp);

        hipMemsetAsync(stats, 0, 2 * Dx * sizeof(float), stream);
        bn_stats<<<256, 256, 0, stream>>>(t, stats);
        bn_norm<<<TOK * Dx / 256, 256, 0, stream>>>(
            t, stats, p32(g1, eD), p16(g1, eD), p32(b1, eD), p16(b1, eD), h, dtp);

        // FF in 8 chunks of 2048 tokens (ffbuf fp32 [2048, 2048])
        for (int ch = 0; ch < 8; ++ch) {
            float* hc = h + (size_t)ch * 2048 * Dx;
            float* tc = t + (size_t)ch * 2048 * Dx;
            gemm_kernel<0, 0, 1><<<dim3(FFx / 64, 2048 / 64), 256, 0, stream>>>(
                hc, p32(W1, e1), p16(W1, e1), p32(bb1, eF), p16(bb1, eF), nullptr, ffbuf, 2048, FFx, Dx, dtp);
            gemm_kernel<0, 0, 2><<<dim3(Dx / 64, 2048 / 64), 256, 0, stream>>>(
                ffbuf, p32(W2, e2), p16(W2, e2), p32(bb2, eD), p16(bb2, eD), hc, tc, 2048, Dx, FFx, dtp);
        }

        hipMemsetAsync(stats, 0, 2 * Dx * sizeof(float), stream);
        bn_stats<<<256, 256, 0, stream>>>(t, stats);
        bn_norm<<<TOK * Dx / 256, 256, 0, stream>>>(
            t, stats, p32(g2, eD), p16(g2, eD), p32(b2, eD), p16(b2, eD), h, dtp);
    }

    out_h_kernel<<<TOK * Dx / 256, 256, 0, stream>>>(h, (float*)d_out);
    out_mean_kernel<<<Bx, Dx, 0, stream>>>(h, (float*)d_out + (size_t)TOK * Dx);
}

// Round 6
// 7408.546 us; speedup vs baseline: 2.8023x; 1.7469x over previous
//
#include <hip/hip_runtime.h>
#include <hip/hip_bf16.h>

// Problem constants
#define Bx 32
#define Nx 512
#define Dx 512
#define Hx 8
#define DKx 64
#define FFx 2048
#define TOK (Bx * Nx)          // 16384 tokens
#define NBC 8                  // batches per attention chunk
#define EPSx 1e-5f

typedef __bf16 bfrag8 __attribute__((ext_vector_type(8)));
typedef float  f32x4  __attribute__((ext_vector_type(4)));

// ---------------------------------------------------------------------------
// Inputs may be fp32 or bf16; detected at runtime on-device. Kernels reading
// INPUT tensors get two candidate pointers plus the flag. Internal fp32.
// ---------------------------------------------------------------------------
__device__ __forceinline__ float ldsel(const void* p32, const void* p16, size_t i, int f32) {
    return f32 ? ((const float*)p32)[i]
               : __bfloat162float(((const __hip_bfloat16*)p16)[i]);
}

__global__ void detect_kernel(const void* __restrict__ x, int* __restrict__ flag)
{
    if (threadIdx.x == 0 && blockIdx.x == 0) {
        const unsigned short* u = (const unsigned short*)x;
        int hits = 0;
        for (int i = 0; i < 256; ++i) {
            int e = (u[i] >> 7) & 0xFF;
            if (e >= 0x86) ++hits;
        }
        *flag = (hits > 8) ? 1 : 0;
    }
}

// ---------------------------------------------------------------------------
__global__ __launch_bounds__(256) void embed_kernel(
    const void* __restrict__ x, const void* __restrict__ We,
    const void* __restrict__ be, float* __restrict__ h, const int* __restrict__ dtp)
{
    const int f32 = *dtp;
    size_t idx = (size_t)blockIdx.x * 256 + threadIdx.x;   // 0 .. TOK*Dx
    int d = idx & (Dx - 1);
    size_t t = idx >> 9;
    float v = ldsel(x, x, t * 2, f32)     * ldsel(We, We, d * 2, f32) +
              ldsel(x, x, t * 2 + 1, f32) * ldsel(We, We, d * 2 + 1, f32) +
              ldsel(be, be, d, f32);
    h[idx] = v;
}

// ---------------------------------------------------------------------------
// Split-bf16 MFMA GEMM: out[m,n] = sum_k A[m,k] * B(n,k)  (+ epilogue)
// Each fp32 operand -> (hi, lo) bf16; per tile 3 MFMAs: Ah*Bh + Ah*Bl + Al*Bh.
// Block: 64x64 tile, 256 thr = 4 waves, each wave a 32x32 quadrant (2x2 of
// 16x16x32 MFMA). BK=32.
// BL: 0 W[n*K+k] (k-contig) ; 1 W[(n>>6)*K*64 + k*64 + (n&63)] (QKV [H,D,DK]) ;
//     2 W[k*N+n] (Wo flat [H*DK, D])
// OL: 0 row-major fp32 ; 1 scatter to [H, NB, N, DK] fp32 (NB = M>>9)
// EPI: 0 plain ; 1 +bias,relu ; 2 +bias(opt)+resid
// ---------------------------------------------------------------------------
template <int BL, int OL, int EPI>
__global__ __launch_bounds__(256) void gemm_mfma(
    const float* __restrict__ A,
    const void* __restrict__ W32, const void* __restrict__ W16,
    const void* __restrict__ bias32, const void* __restrict__ bias16,
    const float* __restrict__ resid,
    float* __restrict__ outp, int M, int N, int K, const int* __restrict__ dtp)
{
    const int f32 = *dtp;
    __shared__ __align__(16) __bf16 Ah[64][40];
    __shared__ __align__(16) __bf16 Al[64][40];
    __shared__ __align__(16) __bf16 Bh[64][40];
    __shared__ __align__(16) __bf16 Bl[64][40];

    const int tid = threadIdx.x;
    const int bm = blockIdx.y * 64;
    const int bn = blockIdx.x * 64;
    const int lane = tid & 63, wv = tid >> 6;
    const int quad = lane >> 4, lrow = lane & 15;
    const int wm = (wv & 1) * 32, wn = (wv >> 1) * 32;

    f32x4 acc[2][2] = {};

    // staging maps
    const int arow = tid >> 2;          // 0..63
    const int akq  = (tid & 3) * 8;     // 0,8,16,24
    const int bncol = tid & 63;         // 0..63 (BL1/2)
    const int bk8   = (tid >> 6) * 8;   // 0,8,16,24

    for (int k0 = 0; k0 < K; k0 += 32) {
        __syncthreads();
        // ---- stage A (always fp32, k-contiguous) ----
        {
            const float* ap = A + (size_t)(bm + arow) * K + k0 + akq;
            f32x4 v0 = *(const f32x4*)ap;
            f32x4 v1 = *(const f32x4*)(ap + 4);
            bfrag8 hi, lo;
            #pragma unroll
            for (int j = 0; j < 4; ++j) {
                __bf16 h0 = (__bf16)v0[j]; hi[j] = h0; lo[j] = (__bf16)(v0[j] - (float)h0);
                __bf16 h1 = (__bf16)v1[j]; hi[j+4] = h1; lo[j+4] = (__bf16)(v1[j] - (float)h1);
            }
            *(bfrag8*)&Ah[arow][akq] = hi;
            *(bfrag8*)&Al[arow][akq] = lo;
        }
        // ---- stage B (input weights: dual dtype) ----
        if constexpr (BL == 0) {
            size_t base = (size_t)(bn + arow) * K + (k0 + akq);
            bfrag8 hi, lo;
            #pragma unroll
            for (int j = 0; j < 8; ++j) {
                float v = ldsel(W32, W16, base + j, f32);
                __bf16 hh = (__bf16)v; hi[j] = hh; lo[j] = (__bf16)(v - (float)hh);
            }
            *(bfrag8*)&Bh[arow][akq] = hi;
            *(bfrag8*)&Bl[arow][akq] = lo;
        } else {
            int gn = bn + bncol;
            bfrag8 hi, lo;
            #pragma unroll
            for (int j = 0; j < 8; ++j) {
                int gk = k0 + bk8 + j;
                size_t widx;
                if constexpr (BL == 1) widx = (size_t)(gn >> 6) * ((size_t)K * 64) + (size_t)gk * 64 + (gn & 63);
                else                   widx = (size_t)gk * N + gn;
                float v = ldsel(W32, W16, widx, f32);
                __bf16 hh = (__bf16)v; hi[j] = hh; lo[j] = (__bf16)(v - (float)hh);
            }
            *(bfrag8*)&Bh[bncol][bk8] = hi;
            *(bfrag8*)&Bl[bncol][bk8] = lo;
        }
        __syncthreads();

        // ---- fragments + 12 MFMAs ----
        bfrag8 a_h0 = *(const bfrag8*)&Ah[wm + lrow][quad * 8];
        bfrag8 a_h1 = *(const bfrag8*)&Ah[wm + 16 + lrow][quad * 8];
        bfrag8 a_l0 = *(const bfrag8*)&Al[wm + lrow][quad * 8];
        bfrag8 a_l1 = *(const bfrag8*)&Al[wm + 16 + lrow][quad * 8];
        bfrag8 b_h0 = *(const bfrag8*)&Bh[wn + lrow][quad * 8];
        bfrag8 b_h1 = *(const bfrag8*)&Bh[wn + 16 + lrow][quad * 8];
        bfrag8 b_l0 = *(const bfrag8*)&Bl[wn + lrow][quad * 8];
        bfrag8 b_l1 = *(const bfrag8*)&Bl[wn + 16 + lrow][quad * 8];

        acc[0][0] = __builtin_amdgcn_mfma_f32_16x16x32_bf16(a_h0, b_h0, acc[0][0], 0, 0, 0);
        acc[0][1] = __builtin_amdgcn_mfma_f32_16x16x32_bf16(a_h0, b_h1, acc[0][1], 0, 0, 0);
        acc[1][0] = __builtin_amdgcn_mfma_f32_16x16x32_bf16(a_h1, b_h0, acc[1][0], 0, 0, 0);
        acc[1][1] = __builtin_amdgcn_mfma_f32_16x16x32_bf16(a_h1, b_h1, acc[1][1], 0, 0, 0);
        acc[0][0] = __builtin_amdgcn_mfma_f32_16x16x32_bf16(a_h0, b_l0, acc[0][0], 0, 0, 0);
        acc[0][1] = __builtin_amdgcn_mfma_f32_16x16x32_bf16(a_h0, b_l1, acc[0][1], 0, 0, 0);
        acc[1][0] = __builtin_amdgcn_mfma_f32_16x16x32_bf16(a_h1, b_l0, acc[1][0], 0, 0, 0);
        acc[1][1] = __builtin_amdgcn_mfma_f32_16x16x32_bf16(a_h1, b_l1, acc[1][1], 0, 0, 0);
        acc[0][0] = __builtin_amdgcn_mfma_f32_16x16x32_bf16(a_l0, b_h0, acc[0][0], 0, 0, 0);
        acc[0][1] = __builtin_amdgcn_mfma_f32_16x16x32_bf16(a_l0, b_h1, acc[0][1], 0, 0, 0);
        acc[1][0] = __builtin_amdgcn_mfma_f32_16x16x32_bf16(a_l1, b_h0, acc[1][0], 0, 0, 0);
        acc[1][1] = __builtin_amdgcn_mfma_f32_16x16x32_bf16(a_l1, b_h1, acc[1][1], 0, 0, 0);
    }

    // ---- epilogue: C[row = quad*4+reg][col = lrow] per 16x16 tile ----
    const int nb = M >> 9;
    #pragma unroll
    for (int mt = 0; mt < 2; ++mt) {
        #pragma unroll
        for (int nt = 0; nt < 2; ++nt) {
            #pragma unroll
            for (int reg = 0; reg < 4; ++reg) {
                int m = bm + wm + mt * 16 + quad * 4 + reg;
                int n = bn + wn + nt * 16 + lrow;
                float v = acc[mt][nt][reg];
                if constexpr (EPI == 1) { v += ldsel(bias32, bias16, n, f32); v = fmaxf(v, 0.f); }
                if constexpr (EPI == 2) {
                    if (bias32) v += ldsel(bias32, bias16, n, f32);
                    v += resid[(size_t)m * N + n];
                }
                if constexpr (OL == 0) {
                    outp[(size_t)m * N + n] = v;
                } else {
                    int head = n >> 6, kk2 = n & 63;
                    int b_ = m >> 9, q = m & 511;   // chunk-local batch
                    size_t oidx = ((((size_t)head * nb + b_) * Nx + q) * DKx) + kk2;
                    outp[oidx] = v;
                }
            }
        }
    }
}

// ---------------------------------------------------------------------------
// Flash-style attention: block = (hb, 64-q-row tile). Q,K,V fp32 [H,NBC,N,DK].
// ---------------------------------------------------------------------------
__global__ __launch_bounds__(256) void attn_kernel(
    const float* __restrict__ Q, const float* __restrict__ K,
    const float* __restrict__ V, float* __restrict__ heads, int b0)
{
    __shared__ float Qs[64][65];
    __shared__ float Ks[64][65];
    __shared__ float Vs[64][65];
    __shared__ float Ss[64][65];
    __shared__ float ml[64], ll[64], al[64];

    const int tid = threadIdx.x;
    const int q0 = blockIdx.x * 64;
    const int hb = blockIdx.y;               // h*NBC + b_local
    const size_t base = (size_t)hb * (Nx * DKx);
    const int tx = tid & 15, ty = tid >> 4;

    #pragma unroll
    for (int i = 0; i < 16; ++i) {
        int idx = tid + i * 256;
        int r = idx >> 6, c = idx & 63;
        Qs[r][c] = Q[base + (size_t)(q0 + r) * DKx + c];
    }
    if (tid < 64) { ml[tid] = -INFINITY; ll[tid] = 0.f; }

    float acc[4][4] = {};

    for (int n0 = 0; n0 < Nx; n0 += 64) {
        __syncthreads();
        #pragma unroll
        for (int i = 0; i < 16; ++i) {
            int idx = tid + i * 256;
            int r = idx >> 6, c = idx & 63;
            Ks[r][c] = K[base + (size_t)(n0 + r) * DKx + c];
            Vs[r][c] = V[base + (size_t)(n0 + r) * DKx + c];
        }
        __syncthreads();

        float s[4][4] = {};
        #pragma unroll
        for (int k = 0; k < DKx; ++k) {
            float a[4], b[4];
            #pragma unroll
            for (int i = 0; i < 4; ++i) a[i] = Qs[ty * 4 + i][k];
            #pragma unroll
            for (int j = 0; j < 4; ++j) b[j] = Ks[tx * 4 + j][k];
            #pragma unroll
            for (int i = 0; i < 4; ++i)
                #pragma unroll
                for (int j = 0; j < 4; ++j) s[i][j] += a[i] * b[j];
        }
        #pragma unroll
        for (int i = 0; i < 4; ++i)
            #pragma unroll
            for (int j = 0; j < 4; ++j) Ss[ty * 4 + i][tx * 4 + j] = s[i][j] * 0.125f;
        __syncthreads();

        if (tid < 64) {
            float rowmax = -INFINITY;
            #pragma unroll 8
            for (int n = 0; n < 64; ++n) rowmax = fmaxf(rowmax, Ss[tid][n]);
            float mold = ml[tid];
            float mnew = fmaxf(mold, rowmax);
            float alpha = __expf(mold - mnew);
            float sum = 0.f;
            #pragma unroll 8
            for (int n = 0; n < 64; ++n) {
                float p = __expf(Ss[tid][n] - mnew);
                Ss[tid][n] = p;
                sum += p;
            }
            ml[tid] = mnew;
            ll[tid] = ll[tid] * alpha + sum;
            al[tid] = alpha;
        }
        __syncthreads();

        float aq[4];
        #pragma unroll
        for (int i = 0; i < 4; ++i) aq[i] = al[ty * 4 + i];
        #pragma unroll
        for (int i = 0; i < 4; ++i)
            #pragma unroll
            for (int j = 0; j < 4; ++j) acc[i][j] *= aq[i];
        #pragma unroll
        for (int n = 0; n < 64; ++n) {
            float a[4], b[4];
            #pragma unroll
            for (int i = 0; i < 4; ++i) a[i] = Ss[ty * 4 + i][n];
            #pragma unroll
            for (int j = 0; j < 4; ++j) b[j] = Vs[n][tx * 4 + j];
            #pragma unroll
            for (int i = 0; i < 4; ++i)
                #pragma unroll
                for (int j = 0; j < 4; ++j) acc[i][j] += a[i] * b[j];
        }
    }
    __syncthreads();

    const int h_ = hb / NBC, b_ = hb % NBC;
    #pragma unroll
    for (int i = 0; i < 4; ++i) {
        int q = ty * 4 + i;
        float invl = 1.f / ll[q];
        size_t tok = (size_t)(b0 + b_) * Nx + (q0 + q);
        #pragma unroll
        for (int j = 0; j < 4; ++j) {
            heads[tok * Dx + h_ * DKx + tx * 4 + j] = acc[i][j] * invl;
        }
    }
}

// ---------------------------------------------------------------------------
__global__ __launch_bounds__(256) void bn_stats(const float* __restrict__ t, float* __restrict__ stats)
{
    int r0 = blockIdx.x * 64;
    int c = threadIdx.x;
    float s0 = 0, q0 = 0, s1 = 0, q1 = 0;
    for (int r = 0; r < 64; ++r) {
        const float* row = t + (size_t)(r0 + r) * Dx;
        float v0 = row[c], v1 = row[c + 256];
        s0 += v0; q0 += v0 * v0; s1 += v1; q1 += v1 * v1;
    }
    atomicAdd(&stats[c], s0);
    atomicAdd(&stats[c + 256], s1);
    atomicAdd(&stats[Dx + c], q0);
    atomicAdd(&stats[Dx + c + 256], q1);
}

__global__ __launch_bounds__(256) void bn_norm(
    const float* __restrict__ t, const float* __restrict__ stats,
    const void* __restrict__ g32, const void* __restrict__ g16,
    const void* __restrict__ b32, const void* __restrict__ b16,
    float* __restrict__ h, const int* __restrict__ dtp)
{
    const int f32 = *dtp;
    size_t idx = (size_t)blockIdx.x * 256 + threadIdx.x;
    int c = idx & (Dx - 1);
    const float invM = 1.f / (float)TOK;
    float mu = stats[c] * invM;
    float var = stats[Dx + c] * invM - mu * mu;
    float v = (t[idx] - mu) * rsqrtf(var + EPSx) * ldsel(g32, g16, c, f32) + ldsel(b32, b16, c, f32);
    h[idx] = v;
}

// ---------------------------------------------------------------------------
__global__ __launch_bounds__(256) void out_h_kernel(const float* __restrict__ h, float* __restrict__ out)
{
    size_t idx = (size_t)blockIdx.x * 256 + threadIdx.x;
    out[idx] = h[idx];
}

__global__ __launch_bounds__(512) void out_mean_kernel(const float* __restrict__ h, float* __restrict__ out2)
{
    int b = blockIdx.x;
    int d = threadIdx.x;
    float s = 0.f;
    for (int n = 0; n < Nx; ++n) s += h[((size_t)b * Nx + n) * Dx + d];
    out2[b * Dx + d] = s * (1.f / (float)Nx);
}

// ---------------------------------------------------------------------------
extern "C" void kernel_launch(void* const* d_in, const int* in_sizes, int n_in,
                              void* d_out, int out_size, void* d_ws, size_t ws_size,
                              hipStream_t stream)
{
    const void* x   = d_in[0];
    const void* We  = d_in[1];
    const void* be  = d_in[2];
    const void* Wq  = d_in[3];
    const void* Wk  = d_in[4];
    const void* Wv  = d_in[5];
    const void* Wo  = d_in[6];
    const void* g1  = d_in[7];
    const void* b1  = d_in[8];
    const void* W1  = d_in[9];
    const void* bb1 = d_in[10];
    const void* W2  = d_in[11];
    const void* bb2 = d_in[12];
    const void* g2  = d_in[13];
    const void* b2  = d_in[14];

    const size_t szWqkv = (size_t)Hx * Dx * DKx;
    const size_t szWo   = (size_t)Hx * DKx * Dx;
    const size_t szW1   = (size_t)FFx * Dx;
    const size_t szW2   = (size_t)Dx * FFx;

    // workspace layout (all fp32): ~126 MB
    const size_t CH = (size_t)Hx * NBC * Nx * DKx;   // 2,097,152 floats (8 MB)
    float* h     = (float*)d_ws;                     // TOK*Dx
    float* t     = h + (size_t)TOK * Dx;             // TOK*Dx
    float* heads = t + (size_t)TOK * Dx;             // TOK*Dx
    float* Qb    = heads + (size_t)TOK * Dx;         // CH
    float* Kb    = Qb + CH;                          // CH
    float* Vb    = Kb + CH;                          // CH
    float* stats = Vb + CH;                          // 1024
    int*   dtp   = (int*)(stats + 2 * Dx);
    float* ffbuf = Qb;  // [2048, 2048] f32 = 16 MB, reuses dead QKV region

    auto p32 = [](const void* p, size_t e) { return (const void*)((const float*)p + e); };
    auto p16 = [](const void* p, size_t e) { return (const void*)((const __hip_bfloat16*)p + e); };

    detect_kernel<<<1, 64, 0, stream>>>(x, dtp);
    embed_kernel<<<TOK * Dx / 256, 256, 0, stream>>>(x, We, be, h, dtp);

    const int chTok = NBC * Nx;                       // 4096 tokens per attn chunk
    const dim3 gQKV(Dx / 64, chTok / 64);             // (8, 64)
    const dim3 gWo(Dx / 64, TOK / 64);                // (8, 256)
    const dim3 gAttn(Nx / 64, Hx * NBC);              // (8, 64)
    for (int l = 0; l < 3; ++l) {
        const size_t eW = (size_t)l * szWqkv, eO = (size_t)l * szWo;
        const size_t e1 = (size_t)l * szW1,  e2 = (size_t)l * szW2;
        const size_t eD = (size_t)l * Dx,    eF = (size_t)l * FFx;

        // attention in 4 chunks of NBC batches
        for (int ch = 0; ch < 4; ++ch) {
            const float* hc = h + (size_t)ch * chTok * Dx;
            gemm_mfma<1, 1, 0><<<gQKV, 256, 0, stream>>>(
                hc, p32(Wq, eW), p16(Wq, eW), nullptr, nullptr, nullptr, Qb, chTok, Dx, Dx, dtp);
            gemm_mfma<1, 1, 0><<<gQKV, 256, 0, stream>>>(
                hc, p32(Wk, eW), p16(Wk, eW), nullptr, nullptr, nullptr, Kb, chTok, Dx, Dx, dtp);
            gemm_mfma<1, 1, 0><<<gQKV, 256, 0, stream>>>(
                hc, p32(Wv, eW), p16(Wv, eW), nullptr, nullptr, nullptr, Vb, chTok, Dx, Dx, dtp);
            attn_kernel<<<gAttn, 256, 0, stream>>>(Qb, Kb, Vb, heads, ch * NBC);
        }

        // output projection + residual: t = h + heads @ Wo_flat
        gemm_mfma<2, 0, 2><<<gWo, 256, 0, stream>>>(
            heads, p32(Wo, eO), p16(Wo, eO), nullptr, nullptr, h, t, TOK, Dx, Dx, dtp);

        hipMemsetAsync(stats, 0, 2 * Dx * sizeof(float), stream);
        bn_stats<<<256, 256, 0, stream>>>(t, stats);
        bn_norm<<<TOK * Dx / 256, 256, 0, stream>>>(
            t, stats, p32(g1, eD), p16(g1, eD), p32(b1, eD), p16(b1, eD), h, dtp);

        // FF in 8 chunks of 2048 tokens (ffbuf fp32 [2048, 2048])
        for (int ch = 0; ch < 8; ++ch) {
            float* hc = h + (size_t)ch * 2048 * Dx;
            float* tc = t + (size_t)ch * 2048 * Dx;
            gemm_mfma<0, 0, 1><<<dim3(FFx / 64, 2048 / 64), 256, 0, stream>>>(
                hc, p32(W1, e1), p16(W1, e1), p32(bb1, eF), p16(bb1, eF), nullptr, ffbuf, 2048, FFx, Dx, dtp);
            gemm_mfma<0, 0, 2><<<dim3(Dx / 64, 2048 / 64), 256, 0, stream>>>(
                ffbuf, p32(W2, e2), p16(W2, e2), p32(bb2, eD), p16(bb2, eD), hc, tc, 2048, Dx, FFx, dtp);
        }

        hipMemsetAsync(stats, 0, 2 * Dx * sizeof(float), stream);
        bn_stats<<<256, 256, 0, stream>>>(t, stats);
        bn_norm<<<TOK * Dx / 256, 256, 0, stream>>>(
            t, stats, p32(g2, eD), p16(g2, eD), p32(b2, eD), p16(b2, eD), h, dtp);
    }

    out_h_kernel<<<TOK * Dx / 256, 256, 0, stream>>>(h, (float*)d_out);
    out_mean_kernel<<<Bx, Dx, 0, stream>>>(h, (float*)d_out + (size_t)TOK * Dx);
}

// Round 8
// 4850.686 us; speedup vs baseline: 4.2799x; 1.5273x over previous
//
#include <hip/hip_runtime.h>
#include <hip/hip_bf16.h>

// Problem constants
#define Bx 32
#define Nx 512
#define Dx 512
#define Hx 8
#define DKx 64
#define FFx 2048
#define TOK (Bx * Nx)          // 16384 tokens
#define NBC 8                  // batches per attention chunk
#define EPSx 1e-5f

typedef __bf16 bfrag8 __attribute__((ext_vector_type(8)));
typedef float  f32x4  __attribute__((ext_vector_type(4)));

struct bf2 { __bf16 hi, lo; };
__device__ __forceinline__ bf2 split2(float v) {
    __bf16 h = (__bf16)v;
    bf2 r; r.hi = h; r.lo = (__bf16)(v - (float)h);
    return r;
}

// ---------------------------------------------------------------------------
__device__ __forceinline__ float ldsel(const void* p32, const void* p16, size_t i, int f32) {
    return f32 ? ((const float*)p32)[i]
               : __bfloat162float(((const __hip_bfloat16*)p16)[i]);
}

__global__ void detect_kernel(const void* __restrict__ x, int* __restrict__ flag)
{
    if (threadIdx.x == 0 && blockIdx.x == 0) {
        const unsigned short* u = (const unsigned short*)x;
        int hits = 0;
        for (int i = 0; i < 256; ++i) {
            int e = (u[i] >> 7) & 0xFF;
            if (e >= 0x86) ++hits;
        }
        *flag = (hits > 8) ? 1 : 0;
    }
}

// ---------------------------------------------------------------------------
__global__ __launch_bounds__(256) void embed_kernel(
    const void* __restrict__ x, const void* __restrict__ We,
    const void* __restrict__ be, float* __restrict__ h, const int* __restrict__ dtp)
{
    const int f32 = *dtp;
    size_t idx = (size_t)blockIdx.x * 256 + threadIdx.x;
    int d = idx & (Dx - 1);
    size_t t = idx >> 9;
    float v = ldsel(x, x, t * 2, f32)     * ldsel(We, We, d * 2, f32) +
              ldsel(x, x, t * 2 + 1, f32) * ldsel(We, We, d * 2 + 1, f32) +
              ldsel(be, be, d, f32);
    h[idx] = v;
}

// ---------------------------------------------------------------------------
// Split-bf16 MFMA GEMM, 128x64 tile, BK=32, 4 waves x (32m x 64n), 24 MFMA/wv/k0.
// BL: 0 W[n*K+k] (k-contig: W1, W2) ; 2 W[k*N+n] (n-contig: Wo flat)
// EPI: 1 +bias,relu ; 2 +bias(opt)+resid
// ---------------------------------------------------------------------------
template <int BL, int EPI>
__global__ __launch_bounds__(256) void gemm_mfma(
    const float* __restrict__ A,
    const void* __restrict__ W32, const void* __restrict__ W16,
    const void* __restrict__ bias32, const void* __restrict__ bias16,
    const float* __restrict__ resid,
    float* __restrict__ outp, int M, int N, int K, const int* __restrict__ dtp)
{
    const int f32 = *dtp;
    __shared__ __align__(16) __bf16 Ah[128][40];
    __shared__ __align__(16) __bf16 Al[128][40];
    __shared__ __align__(16) __bf16 Bh[64][40];
    __shared__ __align__(16) __bf16 Bl[64][40];

    const int tid = threadIdx.x;
    const int bm = blockIdx.y * 128;
    const int bn = blockIdx.x * 64;
    const int lane = tid & 63, wv = tid >> 6;
    const int quad = lane >> 4, lrow = lane & 15;
    const int wm = wv * 32;

    f32x4 acc[2][4] = {};

    const int ar = tid >> 1, akq = (tid & 1) * 16;

    for (int k0 = 0; k0 < K; k0 += 32) {
        __syncthreads();
        // ---- stage A: 128x32 fp32 -> hi/lo ----
        {
            const float* ap = A + (size_t)(bm + ar) * K + k0 + akq;
            #pragma unroll
            for (int half = 0; half < 2; ++half) {
                f32x4 v0 = *(const f32x4*)(ap + half * 8);
                f32x4 v1 = *(const f32x4*)(ap + half * 8 + 4);
                bfrag8 hi, lo;
                #pragma unroll
                for (int j = 0; j < 4; ++j) {
                    bf2 s0 = split2(v0[j]); hi[j] = s0.hi; lo[j] = s0.lo;
                    bf2 s1 = split2(v1[j]); hi[j + 4] = s1.hi; lo[j + 4] = s1.lo;
                }
                *(bfrag8*)&Ah[ar][akq + half * 8] = hi;
                *(bfrag8*)&Al[ar][akq + half * 8] = lo;
            }
        }
        // ---- stage B: 64x32 ----
        if constexpr (BL == 0) {
            const int br = tid >> 2, bkq = (tid & 3) * 8;
            bfrag8 hi, lo;
            if (f32) {
                const float* wp = (const float*)W32 + (size_t)(bn + br) * K + k0 + bkq;
                f32x4 v0 = *(const f32x4*)wp;
                f32x4 v1 = *(const f32x4*)(wp + 4);
                #pragma unroll
                for (int j = 0; j < 4; ++j) {
                    bf2 s0 = split2(v0[j]); hi[j] = s0.hi; lo[j] = s0.lo;
                    bf2 s1 = split2(v1[j]); hi[j + 4] = s1.hi; lo[j + 4] = s1.lo;
                }
            } else {
                size_t base = (size_t)(bn + br) * K + k0 + bkq;
                #pragma unroll
                for (int j = 0; j < 8; ++j) {
                    bf2 s = split2(ldsel(W32, W16, base + j, 0));
                    hi[j] = s.hi; lo[j] = s.lo;
                }
            }
            *(bfrag8*)&Bh[br][bkq] = hi;
            *(bfrag8*)&Bl[br][bkq] = lo;
        } else {
            const int bgk = tid >> 3, bn8 = (tid & 7) * 8;
            if (f32) {
                const float* wp = (const float*)W32 + (size_t)(k0 + bgk) * N + bn + bn8;
                f32x4 v0 = *(const f32x4*)wp;
                f32x4 v1 = *(const f32x4*)(wp + 4);
                #pragma unroll
                for (int j = 0; j < 4; ++j) {
                    bf2 s0 = split2(v0[j]); Bh[bn8 + j][bgk] = s0.hi; Bl[bn8 + j][bgk] = s0.lo;
                    bf2 s1 = split2(v1[j]); Bh[bn8 + 4 + j][bgk] = s1.hi; Bl[bn8 + 4 + j][bgk] = s1.lo;
                }
            } else {
                #pragma unroll
                for (int j = 0; j < 8; ++j) {
                    size_t widx = (size_t)(k0 + bgk) * N + bn + bn8 + j;
                    bf2 s = split2(ldsel(W32, W16, widx, 0));
                    Bh[bn8 + j][bgk] = s.hi; Bl[bn8 + j][bgk] = s.lo;
                }
            }
        }
        __syncthreads();

        bfrag8 ah[2], alo[2], bh[4], blo[4];
        #pragma unroll
        for (int mt = 0; mt < 2; ++mt) {
            ah[mt]  = *(const bfrag8*)&Ah[wm + mt * 16 + lrow][quad * 8];
            alo[mt] = *(const bfrag8*)&Al[wm + mt * 16 + lrow][quad * 8];
        }
        #pragma unroll
        for (int nt = 0; nt < 4; ++nt) {
            bh[nt]  = *(const bfrag8*)&Bh[nt * 16 + lrow][quad * 8];
            blo[nt] = *(const bfrag8*)&Bl[nt * 16 + lrow][quad * 8];
        }
        #pragma unroll
        for (int mt = 0; mt < 2; ++mt)
            #pragma unroll
            for (int nt = 0; nt < 4; ++nt) {
                acc[mt][nt] = __builtin_amdgcn_mfma_f32_16x16x32_bf16(ah[mt],  bh[nt],  acc[mt][nt], 0, 0, 0);
                acc[mt][nt] = __builtin_amdgcn_mfma_f32_16x16x32_bf16(ah[mt],  blo[nt], acc[mt][nt], 0, 0, 0);
                acc[mt][nt] = __builtin_amdgcn_mfma_f32_16x16x32_bf16(alo[mt], bh[nt],  acc[mt][nt], 0, 0, 0);
            }
    }

    #pragma unroll
    for (int mt = 0; mt < 2; ++mt)
        #pragma unroll
        for (int nt = 0; nt < 4; ++nt)
            #pragma unroll
            for (int reg = 0; reg < 4; ++reg) {
                int m = bm + wm + mt * 16 + quad * 4 + reg;
                int n = bn + nt * 16 + lrow;
                float v = acc[mt][nt][reg];
                if constexpr (EPI == 1) { v += ldsel(bias32, bias16, n, f32); v = fmaxf(v, 0.f); }
                if constexpr (EPI == 2) {
                    if (bias32) v += ldsel(bias32, bias16, n, f32);
                    v += resid[(size_t)m * N + n];
                }
                outp[(size_t)m * N + n] = v;
            }
}

// ---------------------------------------------------------------------------
// Fused QKV projection: N=1536 (3 x 512), W [H,D,DK] per proj; scatter to
// [H, NB, N, DK]. Each 64-col n-block lies in exactly one projection/head.
// ---------------------------------------------------------------------------
__global__ __launch_bounds__(256) void qkv_mfma(
    const float* __restrict__ A,
    const void* __restrict__ Wq32, const void* __restrict__ Wq16,
    const void* __restrict__ Wk32, const void* __restrict__ Wk16,
    const void* __restrict__ Wv32, const void* __restrict__ Wv16,
    float* __restrict__ Qo, float* __restrict__ Ko, float* __restrict__ Vo,
    int M, int K, const int* __restrict__ dtp)
{
    const int f32 = *dtp;
    __shared__ __align__(16) __bf16 Ah[128][40];
    __shared__ __align__(16) __bf16 Al[128][40];
    __shared__ __align__(16) __bf16 Bh[64][40];
    __shared__ __align__(16) __bf16 Bl[64][40];

    const int tid = threadIdx.x;
    const int bm = blockIdx.y * 128;
    const int bn = blockIdx.x * 64;            // 0..1536
    const int sel = bn >> 9;                   // which projection
    const int head = (bn & 511) >> 6;          // which head (64-aligned)
    const void* W32 = (sel == 0) ? Wq32 : (sel == 1) ? Wk32 : Wv32;
    const void* W16 = (sel == 0) ? Wq16 : (sel == 1) ? Wk16 : Wv16;
    float* outp = (sel == 0) ? Qo : (sel == 1) ? Ko : Vo;

    const int lane = tid & 63, wv = tid >> 6;
    const int quad = lane >> 4, lrow = lane & 15;
    const int wm = wv * 32;

    f32x4 acc[2][4] = {};
    const int ar = tid >> 1, akq = (tid & 1) * 16;
    const size_t wbase = (size_t)head * K * 64;

    for (int k0 = 0; k0 < K; k0 += 32) {
        __syncthreads();
        {
            const float* ap = A + (size_t)(bm + ar) * K + k0 + akq;
            #pragma unroll
            for (int half = 0; half < 2; ++half) {
                f32x4 v0 = *(const f32x4*)(ap + half * 8);
                f32x4 v1 = *(const f32x4*)(ap + half * 8 + 4);
                bfrag8 hi, lo;
                #pragma unroll
                for (int j = 0; j < 4; ++j) {
                    bf2 s0 = split2(v0[j]); hi[j] = s0.hi; lo[j] = s0.lo;
                    bf2 s1 = split2(v1[j]); hi[j + 4] = s1.hi; lo[j + 4] = s1.lo;
                }
                *(bfrag8*)&Ah[ar][akq + half * 8] = hi;
                *(bfrag8*)&Al[ar][akq + half * 8] = lo;
            }
        }
        {   // B: W[head][k][dk], dk-contig (64 wide)
            const int bgk = tid >> 3, bn8 = (tid & 7) * 8;
            if (f32) {
                const float* wp = (const float*)W32 + wbase + (size_t)(k0 + bgk) * 64 + bn8;
                f32x4 v0 = *(const f32x4*)wp;
                f32x4 v1 = *(const f32x4*)(wp + 4);
                #pragma unroll
                for (int j = 0; j < 4; ++j) {
                    bf2 s0 = split2(v0[j]); Bh[bn8 + j][bgk] = s0.hi; Bl[bn8 + j][bgk] = s0.lo;
                    bf2 s1 = split2(v1[j]); Bh[bn8 + 4 + j][bgk] = s1.hi; Bl[bn8 + 4 + j][bgk] = s1.lo;
                }
            } else {
                #pragma unroll
                for (int j = 0; j < 8; ++j) {
                    size_t widx = wbase + (size_t)(k0 + bgk) * 64 + bn8 + j;
                    bf2 s = split2(ldsel(W32, W16, widx, 0));
                    Bh[bn8 + j][bgk] = s.hi; Bl[bn8 + j][bgk] = s.lo;
                }
            }
        }
        __syncthreads();

        bfrag8 ah[2], alo[2], bh[4], blo[4];
        #pragma unroll
        for (int mt = 0; mt < 2; ++mt) {
            ah[mt]  = *(const bfrag8*)&Ah[wm + mt * 16 + lrow][quad * 8];
            alo[mt] = *(const bfrag8*)&Al[wm + mt * 16 + lrow][quad * 8];
        }
        #pragma unroll
        for (int nt = 0; nt < 4; ++nt) {
            bh[nt]  = *(const bfrag8*)&Bh[nt * 16 + lrow][quad * 8];
            blo[nt] = *(const bfrag8*)&Bl[nt * 16 + lrow][quad * 8];
        }
        #pragma unroll
        for (int mt = 0; mt < 2; ++mt)
            #pragma unroll
            for (int nt = 0; nt < 4; ++nt) {
                acc[mt][nt] = __builtin_amdgcn_mfma_f32_16x16x32_bf16(ah[mt],  bh[nt],  acc[mt][nt], 0, 0, 0);
                acc[mt][nt] = __builtin_amdgcn_mfma_f32_16x16x32_bf16(ah[mt],  blo[nt], acc[mt][nt], 0, 0, 0);
                acc[mt][nt] = __builtin_amdgcn_mfma_f32_16x16x32_bf16(alo[mt], bh[nt],  acc[mt][nt], 0, 0, 0);
            }
    }

    const int nb = M >> 9;
    #pragma unroll
    for (int mt = 0; mt < 2; ++mt)
        #pragma unroll
        for (int nt = 0; nt < 4; ++nt)
            #pragma unroll
            for (int reg = 0; reg < 4; ++reg) {
                int m = bm + wm + mt * 16 + quad * 4 + reg;
                int dk = nt * 16 + lrow;
                int b_ = m >> 9, q = m & 511;
                size_t oidx = ((((size_t)head * nb + b_) * Nx + q) * DKx) + dk;
                outp[oidx] = acc[mt][nt][reg];
            }
}

// ---------------------------------------------------------------------------
// MFMA flash attention: block = (hb, 64-q tile). Q,K split-bf16 for scores;
// P,V plain bf16 for PV. Online softmax in LDS.
// ---------------------------------------------------------------------------
__global__ __launch_bounds__(256) void attn_kernel(
    const float* __restrict__ Q, const float* __restrict__ K,
    const float* __restrict__ V, float* __restrict__ heads, int b0)
{
    __shared__ __align__(16) __bf16 Qh[64][72], Ql[64][72];
    __shared__ __align__(16) __bf16 Kh[64][72], Kl[64][72];
    __shared__ __align__(16) __bf16 Vt[64][72];
    __shared__ __align__(16) __bf16 Pp[64][72];
    __shared__ float Ss[64][66];
    __shared__ float ml[64], ll[64], al[64];

    const int tid = threadIdx.x;
    const int q0 = blockIdx.x * 64;
    const int hb = blockIdx.y;                 // h*NBC + b_local
    const size_t base = (size_t)hb * (Nx * DKx);
    const int lane = tid & 63, wv = tid >> 6;
    const int quad = lane >> 4, lrow = lane & 15;
    const int wm = (wv & 1) * 32, wn = (wv >> 1) * 32;

    // stage Q (once): [q][dk] -> hi/lo
    {
        const int r = tid >> 2, c16 = (tid & 3) * 16;
        const float* qp = Q + base + (size_t)(q0 + r) * DKx + c16;
        #pragma unroll
        for (int half = 0; half < 2; ++half) {
            f32x4 v0 = *(const f32x4*)(qp + half * 8);
            f32x4 v1 = *(const f32x4*)(qp + half * 8 + 4);
            bfrag8 hi, lo;
            #pragma unroll
            for (int j = 0; j < 4; ++j) {
                bf2 s0 = split2(v0[j]); hi[j] = s0.hi; lo[j] = s0.lo;
                bf2 s1 = split2(v1[j]); hi[j + 4] = s1.hi; lo[j + 4] = s1.lo;
            }
            *(bfrag8*)&Qh[r][c16 + half * 8] = hi;
            *(bfrag8*)&Ql[r][c16 + half * 8] = lo;
        }
    }
    if (tid < 64) { ml[tid] = -INFINITY; ll[tid] = 0.f; }

    f32x4 accO[2][2] = {};

    for (int n0 = 0; n0 < Nx; n0 += 64) {
        __syncthreads();   // prev iter done with Kh/Kl/Vt/Pp
        // stage K tile: [n][dk] -> hi/lo ; V tile transposed -> Vt[dk][n]
        {
            const int r = tid >> 2, c16 = (tid & 3) * 16;
            const float* kp = K + base + (size_t)(n0 + r) * DKx + c16;
            #pragma unroll
            for (int half = 0; half < 2; ++half) {
                f32x4 v0 = *(const f32x4*)(kp + half * 8);
                f32x4 v1 = *(const f32x4*)(kp + half * 8 + 4);
                bfrag8 hi, lo;
                #pragma unroll
                for (int j = 0; j < 4; ++j) {
                    bf2 s0 = split2(v0[j]); hi[j] = s0.hi; lo[j] = s0.lo;
                    bf2 s1 = split2(v1[j]); hi[j + 4] = s1.hi; lo[j + 4] = s1.lo;
                }
                *(bfrag8*)&Kh[r][c16 + half * 8] = hi;
                *(bfrag8*)&Kl[r][c16 + half * 8] = lo;
            }
            const float* vp = V + base + (size_t)(n0 + r) * DKx + c16;
            #pragma unroll
            for (int half = 0; half < 2; ++half) {
                f32x4 v0 = *(const f32x4*)(vp + half * 8);
                f32x4 v1 = *(const f32x4*)(vp + half * 8 + 4);
                #pragma unroll
                for (int j = 0; j < 4; ++j) {
                    Vt[c16 + half * 8 + j][r]     = (__bf16)v0[j];
                    Vt[c16 + half * 8 + 4 + j][r] = (__bf16)v1[j];
                }
            }
        }
        __syncthreads();

        // scores: S = 0.125 * Q K^T  (split: QhKh + QhKl + QlKh)
        f32x4 accS[2][2] = {};
        #pragma unroll
        for (int ks = 0; ks < 2; ++ks) {
            bfrag8 ah[2], alo[2], bh[2], blo[2];
            #pragma unroll
            for (int mt = 0; mt < 2; ++mt) {
                ah[mt]  = *(const bfrag8*)&Qh[wm + mt * 16 + lrow][ks * 32 + quad * 8];
                alo[mt] = *(const bfrag8*)&Ql[wm + mt * 16 + lrow][ks * 32 + quad * 8];
            }
            #pragma unroll
            for (int nt = 0; nt < 2; ++nt) {
                bh[nt]  = *(const bfrag8*)&Kh[wn + nt * 16 + lrow][ks * 32 + quad * 8];
                blo[nt] = *(const bfrag8*)&Kl[wn + nt * 16 + lrow][ks * 32 + quad * 8];
            }
            #pragma unroll
            for (int mt = 0; mt < 2; ++mt)
                #pragma unroll
                for (int nt = 0; nt < 2; ++nt) {
                    accS[mt][nt] = __builtin_amdgcn_mfma_f32_16x16x32_bf16(ah[mt],  bh[nt],  accS[mt][nt], 0, 0, 0);
                    accS[mt][nt] = __builtin_amdgcn_mfma_f32_16x16x32_bf16(ah[mt],  blo[nt], accS[mt][nt], 0, 0, 0);
                    accS[mt][nt] = __builtin_amdgcn_mfma_f32_16x16x32_bf16(alo[mt], bh[nt],  accS[mt][nt], 0, 0, 0);
                }
        }
        #pragma unroll
        for (int mt = 0; mt < 2; ++mt)
            #pragma unroll
            for (int nt = 0; nt < 2; ++nt)
                #pragma unroll
                for (int reg = 0; reg < 4; ++reg)
                    Ss[wm + mt * 16 + quad * 4 + reg][wn + nt * 16 + lrow] = accS[mt][nt][reg] * 0.125f;
        __syncthreads();

        // online softmax per q row -> P (bf16)
        if (tid < 64) {
            float rowmax = -INFINITY;
            #pragma unroll 8
            for (int n = 0; n < 64; ++n) rowmax = fmaxf(rowmax, Ss[tid][n]);
            float mold = ml[tid];
            float mnew = fmaxf(mold, rowmax);
            float alpha = __expf(mold - mnew);
            float sum = 0.f;
            #pragma unroll 8
            for (int n = 0; n < 64; ++n) {
                float p = __expf(Ss[tid][n] - mnew);
                Pp[tid][n] = (__bf16)p;
                sum += p;
            }
            ml[tid] = mnew;
            ll[tid] = ll[tid] * alpha + sum;
            al[tid] = alpha;
        }
        __syncthreads();

        // O = O*alpha + P @ V   (plain bf16)
        #pragma unroll
        for (int mt = 0; mt < 2; ++mt) {
            float a0 = al[wm + mt * 16 + quad * 4 + 0];
            float a1 = al[wm + mt * 16 + quad * 4 + 1];
            float a2 = al[wm + mt * 16 + quad * 4 + 2];
            float a3 = al[wm + mt * 16 + quad * 4 + 3];
            #pragma unroll
            for (int nt = 0; nt < 2; ++nt) {
                accO[mt][nt][0] *= a0; accO[mt][nt][1] *= a1;
                accO[mt][nt][2] *= a2; accO[mt][nt][3] *= a3;
            }
        }
        #pragma unroll
        for (int ks = 0; ks < 2; ++ks) {
            bfrag8 ap[2], bv[2];
            #pragma unroll
            for (int mt = 0; mt < 2; ++mt)
                ap[mt] = *(const bfrag8*)&Pp[wm + mt * 16 + lrow][ks * 32 + quad * 8];
            #pragma unroll
            for (int nt = 0; nt < 2; ++nt)
                bv[nt] = *(const bfrag8*)&Vt[wn + nt * 16 + lrow][ks * 32 + quad * 8];
            #pragma unroll
            for (int mt = 0; mt < 2; ++mt)
                #pragma unroll
                for (int nt = 0; nt < 2; ++nt)
                    accO[mt][nt] = __builtin_amdgcn_mfma_f32_16x16x32_bf16(ap[mt], bv[nt], accO[mt][nt], 0, 0, 0);
        }
    }
    __syncthreads();

    const int h_ = hb / NBC, b_ = hb % NBC;
    #pragma unroll
    for (int mt = 0; mt < 2; ++mt)
        #pragma unroll
        for (int reg = 0; reg < 4; ++reg) {
            int qrow = wm + mt * 16 + quad * 4 + reg;
            float invl = 1.f / ll[qrow];
            size_t tok = (size_t)(b0 + b_) * Nx + (q0 + qrow);
            #pragma unroll
            for (int nt = 0; nt < 2; ++nt) {
                int dk = wn + nt * 16 + lrow;
                heads[tok * Dx + h_ * DKx + dk] = accO[mt][nt][reg] * invl;
            }
        }
}

// ---------------------------------------------------------------------------
__global__ __launch_bounds__(256) void bn_stats(const float* __restrict__ t, float* __restrict__ stats)
{
    int r0 = blockIdx.x * 64;
    int c = threadIdx.x;
    float s0 = 0, q0 = 0, s1 = 0, q1 = 0;
    for (int r = 0; r < 64; ++r) {
        const float* row = t + (size_t)(r0 + r) * Dx;
        float v0 = row[c], v1 = row[c + 256];
        s0 += v0; q0 += v0 * v0; s1 += v1; q1 += v1 * v1;
    }
    atomicAdd(&stats[c], s0);
    atomicAdd(&stats[c + 256], s1);
    atomicAdd(&stats[Dx + c], q0);
    atomicAdd(&stats[Dx + c + 256], q1);
}

__global__ __launch_bounds__(256) void bn_norm(
    const float* __restrict__ t, const float* __restrict__ stats,
    const void* __restrict__ g32, const void* __restrict__ g16,
    const void* __restrict__ b32, const void* __restrict__ b16,
    float* __restrict__ h, const int* __restrict__ dtp)
{
    const int f32 = *dtp;
    size_t idx = (size_t)blockIdx.x * 256 + threadIdx.x;
    int c = idx & (Dx - 1);
    const float invM = 1.f / (float)TOK;
    float mu = stats[c] * invM;
    float var = stats[Dx + c] * invM - mu * mu;
    float v = (t[idx] - mu) * rsqrtf(var + EPSx) * ldsel(g32, g16, c, f32) + ldsel(b32, b16, c, f32);
    h[idx] = v;
}

// ---------------------------------------------------------------------------
__global__ __launch_bounds__(256) void out_h_kernel(const float* __restrict__ h, float* __restrict__ out)
{
    size_t idx = (size_t)blockIdx.x * 256 + threadIdx.x;
    out[idx] = h[idx];
}

__global__ __launch_bounds__(512) void out_mean_kernel(const float* __restrict__ h, float* __restrict__ out2)
{
    int b = blockIdx.x;
    int d = threadIdx.x;
    float s = 0.f;
    for (int n = 0; n < Nx; ++n) s += h[((size_t)b * Nx + n) * Dx + d];
    out2[b * Dx + d] = s * (1.f / (float)Nx);
}

// ---------------------------------------------------------------------------
extern "C" void kernel_launch(void* const* d_in, const int* in_sizes, int n_in,
                              void* d_out, int out_size, void* d_ws, size_t ws_size,
                              hipStream_t stream)
{
    const void* x   = d_in[0];
    const void* We  = d_in[1];
    const void* be  = d_in[2];
    const void* Wq  = d_in[3];
    const void* Wk  = d_in[4];
    const void* Wv  = d_in[5];
    const void* Wo  = d_in[6];
    const void* g1  = d_in[7];
    const void* b1  = d_in[8];
    const void* W1  = d_in[9];
    const void* bb1 = d_in[10];
    const void* W2  = d_in[11];
    const void* bb2 = d_in[12];
    const void* g2  = d_in[13];
    const void* b2  = d_in[14];

    const size_t szWqkv = (size_t)Hx * Dx * DKx;
    const size_t szWo   = (size_t)Hx * DKx * Dx;
    const size_t szW1   = (size_t)FFx * Dx;
    const size_t szW2   = (size_t)Dx * FFx;

    // workspace layout (all fp32): ~126 MB
    const size_t CH = (size_t)Hx * NBC * Nx * DKx;   // 2,097,152 floats
    float* h     = (float*)d_ws;
    float* t     = h + (size_t)TOK * Dx;
    float* heads = t + (size_t)TOK * Dx;
    float* Qb    = heads + (size_t)TOK * Dx;
    float* Kb    = Qb + CH;
    float* Vb    = Kb + CH;
    float* stats = Vb + CH;
    int*   dtp   = (int*)(stats + 2 * Dx);
    float* ffbuf = Qb;  // [2048,2048] f32 reuses Qb+Kb region

    auto p32 = [](const void* p, size_t e) { return (const void*)((const float*)p + e); };
    auto p16 = [](const void* p, size_t e) { return (const void*)((const __hip_bfloat16*)p + e); };

    detect_kernel<<<1, 64, 0, stream>>>(x, dtp);
    embed_kernel<<<TOK * Dx / 256, 256, 0, stream>>>(x, We, be, h, dtp);

    const int chTok = NBC * Nx;                       // 4096
    const dim3 gQKV(24, chTok / 128);                 // (24, 32)
    const dim3 gWo(Dx / 64, TOK / 128);               // (8, 128)
    const dim3 gAttn(Nx / 64, Hx * NBC);              // (8, 64)
    for (int l = 0; l < 3; ++l) {
        const size_t eW = (size_t)l * szWqkv, eO = (size_t)l * szWo;
        const size_t e1 = (size_t)l * szW1,  e2 = (size_t)l * szW2;
        const size_t eD = (size_t)l * Dx,    eF = (size_t)l * FFx;

        for (int ch = 0; ch < 4; ++ch) {
            const float* hc = h + (size_t)ch * chTok * Dx;
            qkv_mfma<<<gQKV, 256, 0, stream>>>(
                hc, p32(Wq, eW), p16(Wq, eW), p32(Wk, eW), p16(Wk, eW),
                p32(Wv, eW), p16(Wv, eW), Qb, Kb, Vb, chTok, Dx, dtp);
            attn_kernel<<<gAttn, 256, 0, stream>>>(Qb, Kb, Vb, heads, ch * NBC);
        }

        // output projection + residual: t = h + heads @ Wo_flat
        gemm_mfma<2, 2><<<gWo, 256, 0, stream>>>(
            heads, p32(Wo, eO), p16(Wo, eO), nullptr, nullptr, h, t, TOK, Dx, Dx, dtp);

        hipMemsetAsync(stats, 0, 2 * Dx * sizeof(float), stream);
        bn_stats<<<256, 256, 0, stream>>>(t, stats);
        bn_norm<<<TOK * Dx / 256, 256, 0, stream>>>(
            t, stats, p32(g1, eD), p16(g1, eD), p32(b1, eD), p16(b1, eD), h, dtp);

        for (int ch = 0; ch < 8; ++ch) {
            float* hc = h + (size_t)ch * 2048 * Dx;
            float* tc = t + (size_t)ch * 2048 * Dx;
            gemm_mfma<0, 1><<<dim3(FFx / 64, 2048 / 128), 256, 0, stream>>>(
                hc, p32(W1, e1), p16(W1, e1), p32(bb1, eF), p16(bb1, eF), nullptr, ffbuf, 2048, FFx, Dx, dtp);
            gemm_mfma<0, 2><<<dim3(Dx / 64, 2048 / 128), 256, 0, stream>>>(
                ffbuf, p32(W2, e2), p16(W2, e2), p32(bb2, eD), p16(bb2, eD), hc, tc, 2048, Dx, FFx, dtp);
        }

        hipMemsetAsync(stats, 0, 2 * Dx * sizeof(float), stream);
        bn_stats<<<256, 256, 0, stream>>>(t, stats);
        bn_norm<<<TOK * Dx / 256, 256, 0, stream>>>(
            t, stats, p32(g2, eD), p16(g2, eD), p32(b2, eD), p16(b2, eD), h, dtp);
    }

    out_h_kernel<<<TOK * Dx / 256, 256, 0, stream>>>(h, (float*)d_out);
    out_mean_kernel<<<Bx, Dx, 0, stream>>>(h, (float*)d_out + (size_t)TOK * Dx);
}

// Round 9
// 3102.602 us; speedup vs baseline: 6.6914x; 1.5634x over previous
//
#include <hip/hip_runtime.h>
#include <hip/hip_bf16.h>

// Problem constants
#define Bx 32
#define Nx 512
#define Dx 512
#define Hx 8
#define DKx 64
#define FFx 2048
#define TOK (Bx * Nx)          // 16384 tokens
#define NBC 8                  // batches per attention chunk
#define EPSx 1e-5f

typedef __bf16 bfrag8 __attribute__((ext_vector_type(8)));
typedef float  f32x4  __attribute__((ext_vector_type(4)));

struct bf2 { __bf16 hi, lo; };
__device__ __forceinline__ bf2 split2(float v) {
    __bf16 h = (__bf16)v;
    bf2 r; r.hi = h; r.lo = (__bf16)(v - (float)h);
    return r;
}

// ---------------------------------------------------------------------------
__device__ __forceinline__ float ldsel(const void* p32, const void* p16, size_t i, int f32) {
    return f32 ? ((const float*)p32)[i]
               : __bfloat162float(((const __hip_bfloat16*)p16)[i]);
}

__global__ void detect_kernel(const void* __restrict__ x, int* __restrict__ flag)
{
    if (threadIdx.x == 0 && blockIdx.x == 0) {
        const unsigned short* u = (const unsigned short*)x;
        int hits = 0;
        for (int i = 0; i < 256; ++i) {
            int e = (u[i] >> 7) & 0xFF;
            if (e >= 0x86) ++hits;
        }
        *flag = (hits > 8) ? 1 : 0;
    }
}

// ---------------------------------------------------------------------------
__global__ __launch_bounds__(256) void embed_kernel(
    const void* __restrict__ x, const void* __restrict__ We,
    const void* __restrict__ be, float* __restrict__ h, const int* __restrict__ dtp)
{
    const int f32 = *dtp;
    size_t idx = (size_t)blockIdx.x * 256 + threadIdx.x;
    int d = idx & (Dx - 1);
    size_t t = idx >> 9;
    float v = ldsel(x, x, t * 2, f32)     * ldsel(We, We, d * 2, f32) +
              ldsel(x, x, t * 2 + 1, f32) * ldsel(We, We, d * 2 + 1, f32) +
              ldsel(be, be, d, f32);
    h[idx] = v;
}

// ---------------------------------------------------------------------------
// Split-bf16 MFMA GEMM, 128x64 tile, BK=32, register-prefetch double buffer.
// BL: 0 W[n*K+k] (k-contig: W1, W2) ; 2 W[k*N+n] (n-contig: Wo flat)
// EPI: 1 +bias,relu ; 2 +bias(opt)+resid
// ---------------------------------------------------------------------------
template <int BL, int EPI>
__global__ __launch_bounds__(256) void gemm_mfma(
    const float* __restrict__ A,
    const void* __restrict__ W32, const void* __restrict__ W16,
    const void* __restrict__ bias32, const void* __restrict__ bias16,
    const float* __restrict__ resid,
    float* __restrict__ outp, int M, int N, int K, const int* __restrict__ dtp)
{
    const int f32 = *dtp;
    __shared__ __align__(16) __bf16 Ah[128][40];
    __shared__ __align__(16) __bf16 Al[128][40];
    __shared__ __align__(16) __bf16 Bh[64][40];
    __shared__ __align__(16) __bf16 Bl[64][40];

    const int tid = threadIdx.x;
    const int bm = blockIdx.y * 128;
    const int bn = blockIdx.x * 64;
    const int lane = tid & 63, wv = tid >> 6;
    const int quad = lane >> 4, lrow = lane & 15;
    const int wm = wv * 32;

    f32x4 acc[2][4] = {};

    const int ar = tid >> 1, akq = (tid & 1) * 16;
    const int br0 = tid >> 2, bkq0 = (tid & 3) * 8;   // BL0
    const int bgk = tid >> 3, bn8 = (tid & 7) * 8;    // BL2

    f32x4 pa[4];     // A prefetch: row ar, cols akq..akq+15
    f32x4 pb[2];     // B prefetch: 8 floats

    auto loadA = [&](int k0) {
        const float* ap = A + (size_t)(bm + ar) * K + k0 + akq;
        pa[0] = *(const f32x4*)ap;
        pa[1] = *(const f32x4*)(ap + 4);
        pa[2] = *(const f32x4*)(ap + 8);
        pa[3] = *(const f32x4*)(ap + 12);
    };
    auto loadB = [&](int k0) {
        if constexpr (BL == 0) {
            if (f32) {
                const float* wp = (const float*)W32 + (size_t)(bn + br0) * K + k0 + bkq0;
                pb[0] = *(const f32x4*)wp;
                pb[1] = *(const f32x4*)(wp + 4);
            } else {
                size_t base = (size_t)(bn + br0) * K + k0 + bkq0;
                #pragma unroll
                for (int j = 0; j < 4; ++j) {
                    pb[0][j] = ldsel(W32, W16, base + j, 0);
                    pb[1][j] = ldsel(W32, W16, base + 4 + j, 0);
                }
            }
        } else {
            if (f32) {
                const float* wp = (const float*)W32 + (size_t)(k0 + bgk) * N + bn + bn8;
                pb[0] = *(const f32x4*)wp;
                pb[1] = *(const f32x4*)(wp + 4);
            } else {
                size_t base = (size_t)(k0 + bgk) * N + bn + bn8;
                #pragma unroll
                for (int j = 0; j < 4; ++j) {
                    pb[0][j] = ldsel(W32, W16, base + j, 0);
                    pb[1][j] = ldsel(W32, W16, base + 4 + j, 0);
                }
            }
        }
    };
    auto storeAB = [&]() {
        #pragma unroll
        for (int half = 0; half < 2; ++half) {
            bfrag8 hi, lo;
            #pragma unroll
            for (int j = 0; j < 4; ++j) {
                bf2 s0 = split2(pa[half * 2][j]);     hi[j] = s0.hi;     lo[j] = s0.lo;
                bf2 s1 = split2(pa[half * 2 + 1][j]); hi[j + 4] = s1.hi; lo[j + 4] = s1.lo;
            }
            *(bfrag8*)&Ah[ar][akq + half * 8] = hi;
            *(bfrag8*)&Al[ar][akq + half * 8] = lo;
        }
        if constexpr (BL == 0) {
            bfrag8 hi, lo;
            #pragma unroll
            for (int j = 0; j < 4; ++j) {
                bf2 s0 = split2(pb[0][j]); hi[j] = s0.hi;     lo[j] = s0.lo;
                bf2 s1 = split2(pb[1][j]); hi[j + 4] = s1.hi; lo[j + 4] = s1.lo;
            }
            *(bfrag8*)&Bh[br0][bkq0] = hi;
            *(bfrag8*)&Bl[br0][bkq0] = lo;
        } else {
            #pragma unroll
            for (int j = 0; j < 4; ++j) {
                bf2 s0 = split2(pb[0][j]); Bh[bn8 + j][bgk] = s0.hi;     Bl[bn8 + j][bgk] = s0.lo;
                bf2 s1 = split2(pb[1][j]); Bh[bn8 + 4 + j][bgk] = s1.hi; Bl[bn8 + 4 + j][bgk] = s1.lo;
            }
        }
    };

    loadA(0); loadB(0);
    for (int k0 = 0; k0 < K; k0 += 32) {
        __syncthreads();         // readers of previous tile done
        storeAB();
        __syncthreads();         // tile ready
        if (k0 + 32 < K) { loadA(k0 + 32); loadB(k0 + 32); }   // prefetch next

        bfrag8 ah[2], alo[2], bh[4], blo[4];
        #pragma unroll
        for (int mt = 0; mt < 2; ++mt) {
            ah[mt]  = *(const bfrag8*)&Ah[wm + mt * 16 + lrow][quad * 8];
            alo[mt] = *(const bfrag8*)&Al[wm + mt * 16 + lrow][quad * 8];
        }
        #pragma unroll
        for (int nt = 0; nt < 4; ++nt) {
            bh[nt]  = *(const bfrag8*)&Bh[nt * 16 + lrow][quad * 8];
            blo[nt] = *(const bfrag8*)&Bl[nt * 16 + lrow][quad * 8];
        }
        #pragma unroll
        for (int mt = 0; mt < 2; ++mt)
            #pragma unroll
            for (int nt = 0; nt < 4; ++nt) {
                acc[mt][nt] = __builtin_amdgcn_mfma_f32_16x16x32_bf16(ah[mt],  bh[nt],  acc[mt][nt], 0, 0, 0);
                acc[mt][nt] = __builtin_amdgcn_mfma_f32_16x16x32_bf16(ah[mt],  blo[nt], acc[mt][nt], 0, 0, 0);
                acc[mt][nt] = __builtin_amdgcn_mfma_f32_16x16x32_bf16(alo[mt], bh[nt],  acc[mt][nt], 0, 0, 0);
            }
    }

    #pragma unroll
    for (int mt = 0; mt < 2; ++mt)
        #pragma unroll
        for (int nt = 0; nt < 4; ++nt)
            #pragma unroll
            for (int reg = 0; reg < 4; ++reg) {
                int m = bm + wm + mt * 16 + quad * 4 + reg;
                int n = bn + nt * 16 + lrow;
                float v = acc[mt][nt][reg];
                if constexpr (EPI == 1) { v += ldsel(bias32, bias16, n, f32); v = fmaxf(v, 0.f); }
                if constexpr (EPI == 2) {
                    if (bias32) v += ldsel(bias32, bias16, n, f32);
                    v += resid[(size_t)m * N + n];
                }
                outp[(size_t)m * N + n] = v;
            }
}

// ---------------------------------------------------------------------------
// Fused QKV projection with register-prefetch double buffer.
// ---------------------------------------------------------------------------
__global__ __launch_bounds__(256) void qkv_mfma(
    const float* __restrict__ A,
    const void* __restrict__ Wq32, const void* __restrict__ Wq16,
    const void* __restrict__ Wk32, const void* __restrict__ Wk16,
    const void* __restrict__ Wv32, const void* __restrict__ Wv16,
    float* __restrict__ Qo, float* __restrict__ Ko, float* __restrict__ Vo,
    int M, int K, const int* __restrict__ dtp)
{
    const int f32 = *dtp;
    __shared__ __align__(16) __bf16 Ah[128][40];
    __shared__ __align__(16) __bf16 Al[128][40];
    __shared__ __align__(16) __bf16 Bh[64][40];
    __shared__ __align__(16) __bf16 Bl[64][40];

    const int tid = threadIdx.x;
    const int bm = blockIdx.y * 128;
    const int bn = blockIdx.x * 64;            // 0..1536
    const int sel = bn >> 9;
    const int head = (bn & 511) >> 6;
    const void* W32 = (sel == 0) ? Wq32 : (sel == 1) ? Wk32 : Wv32;
    const void* W16 = (sel == 0) ? Wq16 : (sel == 1) ? Wk16 : Wv16;
    float* outp = (sel == 0) ? Qo : (sel == 1) ? Ko : Vo;

    const int lane = tid & 63, wv = tid >> 6;
    const int quad = lane >> 4, lrow = lane & 15;
    const int wm = wv * 32;

    f32x4 acc[2][4] = {};
    const int ar = tid >> 1, akq = (tid & 1) * 16;
    const int bgk = tid >> 3, bn8 = (tid & 7) * 8;
    const size_t wbase = (size_t)head * K * 64;

    f32x4 pa[4];
    f32x4 pb[2];

    auto loadA = [&](int k0) {
        const float* ap = A + (size_t)(bm + ar) * K + k0 + akq;
        pa[0] = *(const f32x4*)ap;
        pa[1] = *(const f32x4*)(ap + 4);
        pa[2] = *(const f32x4*)(ap + 8);
        pa[3] = *(const f32x4*)(ap + 12);
    };
    auto loadB = [&](int k0) {
        if (f32) {
            const float* wp = (const float*)W32 + wbase + (size_t)(k0 + bgk) * 64 + bn8;
            pb[0] = *(const f32x4*)wp;
            pb[1] = *(const f32x4*)(wp + 4);
        } else {
            size_t base = wbase + (size_t)(k0 + bgk) * 64 + bn8;
            #pragma unroll
            for (int j = 0; j < 4; ++j) {
                pb[0][j] = ldsel(W32, W16, base + j, 0);
                pb[1][j] = ldsel(W32, W16, base + 4 + j, 0);
            }
        }
    };
    auto storeAB = [&]() {
        #pragma unroll
        for (int half = 0; half < 2; ++half) {
            bfrag8 hi, lo;
            #pragma unroll
            for (int j = 0; j < 4; ++j) {
                bf2 s0 = split2(pa[half * 2][j]);     hi[j] = s0.hi;     lo[j] = s0.lo;
                bf2 s1 = split2(pa[half * 2 + 1][j]); hi[j + 4] = s1.hi; lo[j + 4] = s1.lo;
            }
            *(bfrag8*)&Ah[ar][akq + half * 8] = hi;
            *(bfrag8*)&Al[ar][akq + half * 8] = lo;
        }
        #pragma unroll
        for (int j = 0; j < 4; ++j) {
            bf2 s0 = split2(pb[0][j]); Bh[bn8 + j][bgk] = s0.hi;     Bl[bn8 + j][bgk] = s0.lo;
            bf2 s1 = split2(pb[1][j]); Bh[bn8 + 4 + j][bgk] = s1.hi; Bl[bn8 + 4 + j][bgk] = s1.lo;
        }
    };

    loadA(0); loadB(0);
    for (int k0 = 0; k0 < K; k0 += 32) {
        __syncthreads();
        storeAB();
        __syncthreads();
        if (k0 + 32 < K) { loadA(k0 + 32); loadB(k0 + 32); }

        bfrag8 ah[2], alo[2], bh[4], blo[4];
        #pragma unroll
        for (int mt = 0; mt < 2; ++mt) {
            ah[mt]  = *(const bfrag8*)&Ah[wm + mt * 16 + lrow][quad * 8];
            alo[mt] = *(const bfrag8*)&Al[wm + mt * 16 + lrow][quad * 8];
        }
        #pragma unroll
        for (int nt = 0; nt < 4; ++nt) {
            bh[nt]  = *(const bfrag8*)&Bh[nt * 16 + lrow][quad * 8];
            blo[nt] = *(const bfrag8*)&Bl[nt * 16 + lrow][quad * 8];
        }
        #pragma unroll
        for (int mt = 0; mt < 2; ++mt)
            #pragma unroll
            for (int nt = 0; nt < 4; ++nt) {
                acc[mt][nt] = __builtin_amdgcn_mfma_f32_16x16x32_bf16(ah[mt],  bh[nt],  acc[mt][nt], 0, 0, 0);
                acc[mt][nt] = __builtin_amdgcn_mfma_f32_16x16x32_bf16(ah[mt],  blo[nt], acc[mt][nt], 0, 0, 0);
                acc[mt][nt] = __builtin_amdgcn_mfma_f32_16x16x32_bf16(alo[mt], bh[nt],  acc[mt][nt], 0, 0, 0);
            }
    }

    const int nb = M >> 9;
    #pragma unroll
    for (int mt = 0; mt < 2; ++mt)
        #pragma unroll
        for (int nt = 0; nt < 4; ++nt)
            #pragma unroll
            for (int reg = 0; reg < 4; ++reg) {
                int m = bm + wm + mt * 16 + quad * 4 + reg;
                int dk = nt * 16 + lrow;
                int b_ = m >> 9, q = m & 511;
                size_t oidx = ((((size_t)head * nb + b_) * Nx + q) * DKx) + dk;
                outp[oidx] = acc[mt][nt][reg];
            }
}

// ---------------------------------------------------------------------------
// MFMA flash attention (unchanged from round 7)
// ---------------------------------------------------------------------------
__global__ __launch_bounds__(256) void attn_kernel(
    const float* __restrict__ Q, const float* __restrict__ K,
    const float* __restrict__ V, float* __restrict__ heads, int b0)
{
    __shared__ __align__(16) __bf16 Qh[64][72], Ql[64][72];
    __shared__ __align__(16) __bf16 Kh[64][72], Kl[64][72];
    __shared__ __align__(16) __bf16 Vt[64][72];
    __shared__ __align__(16) __bf16 Pp[64][72];
    __shared__ float Ss[64][66];
    __shared__ float ml[64], ll[64], al[64];

    const int tid = threadIdx.x;
    const int q0 = blockIdx.x * 64;
    const int hb = blockIdx.y;
    const size_t base = (size_t)hb * (Nx * DKx);
    const int lane = tid & 63, wv = tid >> 6;
    const int quad = lane >> 4, lrow = lane & 15;
    const int wm = (wv & 1) * 32, wn = (wv >> 1) * 32;

    {
        const int r = tid >> 2, c16 = (tid & 3) * 16;
        const float* qp = Q + base + (size_t)(q0 + r) * DKx + c16;
        #pragma unroll
        for (int half = 0; half < 2; ++half) {
            f32x4 v0 = *(const f32x4*)(qp + half * 8);
            f32x4 v1 = *(const f32x4*)(qp + half * 8 + 4);
            bfrag8 hi, lo;
            #pragma unroll
            for (int j = 0; j < 4; ++j) {
                bf2 s0 = split2(v0[j]); hi[j] = s0.hi; lo[j] = s0.lo;
                bf2 s1 = split2(v1[j]); hi[j + 4] = s1.hi; lo[j + 4] = s1.lo;
            }
            *(bfrag8*)&Qh[r][c16 + half * 8] = hi;
            *(bfrag8*)&Ql[r][c16 + half * 8] = lo;
        }
    }
    if (tid < 64) { ml[tid] = -INFINITY; ll[tid] = 0.f; }

    f32x4 accO[2][2] = {};

    for (int n0 = 0; n0 < Nx; n0 += 64) {
        __syncthreads();
        {
            const int r = tid >> 2, c16 = (tid & 3) * 16;
            const float* kp = K + base + (size_t)(n0 + r) * DKx + c16;
            #pragma unroll
            for (int half = 0; half < 2; ++half) {
                f32x4 v0 = *(const f32x4*)(kp + half * 8);
                f32x4 v1 = *(const f32x4*)(kp + half * 8 + 4);
                bfrag8 hi, lo;
                #pragma unroll
                for (int j = 0; j < 4; ++j) {
                    bf2 s0 = split2(v0[j]); hi[j] = s0.hi; lo[j] = s0.lo;
                    bf2 s1 = split2(v1[j]); hi[j + 4] = s1.hi; lo[j + 4] = s1.lo;
                }
                *(bfrag8*)&Kh[r][c16 + half * 8] = hi;
                *(bfrag8*)&Kl[r][c16 + half * 8] = lo;
            }
            const float* vp = V + base + (size_t)(n0 + r) * DKx + c16;
            #pragma unroll
            for (int half = 0; half < 2; ++half) {
                f32x4 v0 = *(const f32x4*)(vp + half * 8);
                f32x4 v1 = *(const f32x4*)(vp + half * 8 + 4);
                #pragma unroll
                for (int j = 0; j < 4; ++j) {
                    Vt[c16 + half * 8 + j][r]     = (__bf16)v0[j];
                    Vt[c16 + half * 8 + 4 + j][r] = (__bf16)v1[j];
                }
            }
        }
        __syncthreads();

        f32x4 accS[2][2] = {};
        #pragma unroll
        for (int ks = 0; ks < 2; ++ks) {
            bfrag8 ah[2], alo[2], bh[2], blo[2];
            #pragma unroll
            for (int mt = 0; mt < 2; ++mt) {
                ah[mt]  = *(const bfrag8*)&Qh[wm + mt * 16 + lrow][ks * 32 + quad * 8];
                alo[mt] = *(const bfrag8*)&Ql[wm + mt * 16 + lrow][ks * 32 + quad * 8];
            }
            #pragma unroll
            for (int nt = 0; nt < 2; ++nt) {
                bh[nt]  = *(const bfrag8*)&Kh[wn + nt * 16 + lrow][ks * 32 + quad * 8];
                blo[nt] = *(const bfrag8*)&Kl[wn + nt * 16 + lrow][ks * 32 + quad * 8];
            }
            #pragma unroll
            for (int mt = 0; mt < 2; ++mt)
                #pragma unroll
                for (int nt = 0; nt < 2; ++nt) {
                    accS[mt][nt] = __builtin_amdgcn_mfma_f32_16x16x32_bf16(ah[mt],  bh[nt],  accS[mt][nt], 0, 0, 0);
                    accS[mt][nt] = __builtin_amdgcn_mfma_f32_16x16x32_bf16(ah[mt],  blo[nt], accS[mt][nt], 0, 0, 0);
                    accS[mt][nt] = __builtin_amdgcn_mfma_f32_16x16x32_bf16(alo[mt], bh[nt],  accS[mt][nt], 0, 0, 0);
                }
        }
        #pragma unroll
        for (int mt = 0; mt < 2; ++mt)
            #pragma unroll
            for (int nt = 0; nt < 2; ++nt)
                #pragma unroll
                for (int reg = 0; reg < 4; ++reg)
                    Ss[wm + mt * 16 + quad * 4 + reg][wn + nt * 16 + lrow] = accS[mt][nt][reg] * 0.125f;
        __syncthreads();

        if (tid < 64) {
            float rowmax = -INFINITY;
            #pragma unroll 8
            for (int n = 0; n < 64; ++n) rowmax = fmaxf(rowmax, Ss[tid][n]);
            float mold = ml[tid];
            float mnew = fmaxf(mold, rowmax);
            float alpha = __expf(mold - mnew);
            float sum = 0.f;
            #pragma unroll 8
            for (int n = 0; n < 64; ++n) {
                float p = __expf(Ss[tid][n] - mnew);
                Pp[tid][n] = (__bf16)p;
                sum += p;
            }
            ml[tid] = mnew;
            ll[tid] = ll[tid] * alpha + sum;
            al[tid] = alpha;
        }
        __syncthreads();

        #pragma unroll
        for (int mt = 0; mt < 2; ++mt) {
            float a0 = al[wm + mt * 16 + quad * 4 + 0];
            float a1 = al[wm + mt * 16 + quad * 4 + 1];
            float a2 = al[wm + mt * 16 + quad * 4 + 2];
            float a3 = al[wm + mt * 16 + quad * 4 + 3];
            #pragma unroll
            for (int nt = 0; nt < 2; ++nt) {
                accO[mt][nt][0] *= a0; accO[mt][nt][1] *= a1;
                accO[mt][nt][2] *= a2; accO[mt][nt][3] *= a3;
            }
        }
        #pragma unroll
        for (int ks = 0; ks < 2; ++ks) {
            bfrag8 ap[2], bv[2];
            #pragma unroll
            for (int mt = 0; mt < 2; ++mt)
                ap[mt] = *(const bfrag8*)&Pp[wm + mt * 16 + lrow][ks * 32 + quad * 8];
            #pragma unroll
            for (int nt = 0; nt < 2; ++nt)
                bv[nt] = *(const bfrag8*)&Vt[wn + nt * 16 + lrow][ks * 32 + quad * 8];
            #pragma unroll
            for (int mt = 0; mt < 2; ++mt)
                #pragma unroll
                for (int nt = 0; nt < 2; ++nt)
                    accO[mt][nt] = __builtin_amdgcn_mfma_f32_16x16x32_bf16(ap[mt], bv[nt], accO[mt][nt], 0, 0, 0);
        }
    }
    __syncthreads();

    const int h_ = hb / NBC, b_ = hb % NBC;
    #pragma unroll
    for (int mt = 0; mt < 2; ++mt)
        #pragma unroll
        for (int reg = 0; reg < 4; ++reg) {
            int qrow = wm + mt * 16 + quad * 4 + reg;
            float invl = 1.f / ll[qrow];
            size_t tok = (size_t)(b0 + b_) * Nx + (q0 + qrow);
            #pragma unroll
            for (int nt = 0; nt < 2; ++nt) {
                int dk = wn + nt * 16 + lrow;
                heads[tok * Dx + h_ * DKx + dk] = accO[mt][nt][reg] * invl;
            }
        }
}

// ---------------------------------------------------------------------------
__global__ __launch_bounds__(256) void bn_stats(const float* __restrict__ t, float* __restrict__ stats)
{
    int r0 = blockIdx.x * 64;
    int c = threadIdx.x;
    float s0 = 0, q0 = 0, s1 = 0, q1 = 0;
    for (int r = 0; r < 64; ++r) {
        const float* row = t + (size_t)(r0 + r) * Dx;
        float v0 = row[c], v1 = row[c + 256];
        s0 += v0; q0 += v0 * v0; s1 += v1; q1 += v1 * v1;
    }
    atomicAdd(&stats[c], s0);
    atomicAdd(&stats[c + 256], s1);
    atomicAdd(&stats[Dx + c], q0);
    atomicAdd(&stats[Dx + c + 256], q1);
}

__global__ __launch_bounds__(256) void bn_norm(
    const float* __restrict__ t, const float* __restrict__ stats,
    const void* __restrict__ g32, const void* __restrict__ g16,
    const void* __restrict__ b32, const void* __restrict__ b16,
    float* __restrict__ h, const int* __restrict__ dtp)
{
    const int f32 = *dtp;
    size_t idx = (size_t)blockIdx.x * 256 + threadIdx.x;
    int c = idx & (Dx - 1);
    const float invM = 1.f / (float)TOK;
    float mu = stats[c] * invM;
    float var = stats[Dx + c] * invM - mu * mu;
    float v = (t[idx] - mu) * rsqrtf(var + EPSx) * ldsel(g32, g16, c, f32) + ldsel(b32, b16, c, f32);
    h[idx] = v;
}

// ---------------------------------------------------------------------------
__global__ __launch_bounds__(256) void out_h_kernel(const float* __restrict__ h, float* __restrict__ out)
{
    size_t idx = (size_t)blockIdx.x * 256 + threadIdx.x;
    out[idx] = h[idx];
}

__global__ __launch_bounds__(512) void out_mean_kernel(const float* __restrict__ h, float* __restrict__ out2)
{
    int b = blockIdx.x;
    int d = threadIdx.x;
    float s = 0.f;
    for (int n = 0; n < Nx; ++n) s += h[((size_t)b * Nx + n) * Dx + d];
    out2[b * Dx + d] = s * (1.f / (float)Nx);
}

// ---------------------------------------------------------------------------
extern "C" void kernel_launch(void* const* d_in, const int* in_sizes, int n_in,
                              void* d_out, int out_size, void* d_ws, size_t ws_size,
                              hipStream_t stream)
{
    const void* x   = d_in[0];
    const void* We  = d_in[1];
    const void* be  = d_in[2];
    const void* Wq  = d_in[3];
    const void* Wk  = d_in[4];
    const void* Wv  = d_in[5];
    const void* Wo  = d_in[6];
    const void* g1  = d_in[7];
    const void* b1  = d_in[8];
    const void* W1  = d_in[9];
    const void* bb1 = d_in[10];
    const void* W2  = d_in[11];
    const void* bb2 = d_in[12];
    const void* g2  = d_in[13];
    const void* b2  = d_in[14];

    const size_t szWqkv = (size_t)Hx * Dx * DKx;
    const size_t szWo   = (size_t)Hx * DKx * Dx;
    const size_t szW1   = (size_t)FFx * Dx;
    const size_t szW2   = (size_t)Dx * FFx;

    // workspace layout (all fp32): ~126 MB
    const size_t CH = (size_t)Hx * NBC * Nx * DKx;   // 2,097,152 floats
    float* h     = (float*)d_ws;
    float* t     = h + (size_t)TOK * Dx;
    float* heads = t + (size_t)TOK * Dx;
    float* Qb    = heads + (size_t)TOK * Dx;
    float* Kb    = Qb + CH;
    float* Vb    = Kb + CH;
    float* stats = Vb + CH;
    int*   dtp   = (int*)(stats + 2 * Dx);
    // ffbuf: [4096, 2048] f32 = 32 MB; reuses heads (dead during FF phase)
    float* ffbuf = heads;

    auto p32 = [](const void* p, size_t e) { return (const void*)((const float*)p + e); };
    auto p16 = [](const void* p, size_t e) { return (const void*)((const __hip_bfloat16*)p + e); };

    detect_kernel<<<1, 64, 0, stream>>>(x, dtp);
    embed_kernel<<<TOK * Dx / 256, 256, 0, stream>>>(x, We, be, h, dtp);

    const int chTok = NBC * Nx;                       // 4096
    const dim3 gQKV(24, chTok / 128);                 // (24, 32)
    const dim3 gWo(Dx / 64, TOK / 128);               // (8, 128)
    const dim3 gAttn(Nx / 64, Hx * NBC);              // (8, 64)
    for (int l = 0; l < 3; ++l) {
        const size_t eW = (size_t)l * szWqkv, eO = (size_t)l * szWo;
        const size_t e1 = (size_t)l * szW1,  e2 = (size_t)l * szW2;
        const size_t eD = (size_t)l * Dx,    eF = (size_t)l * FFx;

        for (int ch = 0; ch < 4; ++ch) {
            const float* hc = h + (size_t)ch * chTok * Dx;
            qkv_mfma<<<gQKV, 256, 0, stream>>>(
                hc, p32(Wq, eW), p16(Wq, eW), p32(Wk, eW), p16(Wk, eW),
                p32(Wv, eW), p16(Wv, eW), Qb, Kb, Vb, chTok, Dx, dtp);
            attn_kernel<<<gAttn, 256, 0, stream>>>(Qb, Kb, Vb, heads, ch * NBC);
        }

        // output projection + residual: t = h + heads @ Wo_flat
        gemm_mfma<2, 2><<<gWo, 256, 0, stream>>>(
            heads, p32(Wo, eO), p16(Wo, eO), nullptr, nullptr, h, t, TOK, Dx, Dx, dtp);

        hipMemsetAsync(stats, 0, 2 * Dx * sizeof(float), stream);
        bn_stats<<<256, 256, 0, stream>>>(t, stats);
        bn_norm<<<TOK * Dx / 256, 256, 0, stream>>>(
            t, stats, p32(g1, eD), p16(g1, eD), p32(b1, eD), p16(b1, eD), h, dtp);

        // FF in 4 chunks of 4096 tokens (ffbuf = heads region, 32 MB)
        for (int ch = 0; ch < 4; ++ch) {
            float* hc = h + (size_t)ch * 4096 * Dx;
            float* tc = t + (size_t)ch * 4096 * Dx;
            gemm_mfma<0, 1><<<dim3(FFx / 64, 4096 / 128), 256, 0, stream>>>(
                hc, p32(W1, e1), p16(W1, e1), p32(bb1, eF), p16(bb1, eF), nullptr, ffbuf, 4096, FFx, Dx, dtp);
            gemm_mfma<0, 2><<<dim3(Dx / 64, 4096 / 128), 256, 0, stream>>>(
                ffbuf, p32(W2, e2), p16(W2, e2), p32(bb2, eD), p16(bb2, eD), hc, tc, 4096, Dx, FFx, dtp);
        }

        hipMemsetAsync(stats, 0, 2 * Dx * sizeof(float), stream);
        bn_stats<<<256, 256, 0, stream>>>(t, stats);
        bn_norm<<<TOK * Dx / 256, 256, 0, stream>>>(
            t, stats, p32(g2, eD), p16(g2, eD), p32(b2, eD), p16(b2, eD), h, dtp);
    }

    out_h_kernel<<<TOK * Dx / 256, 256, 0, stream>>>(h, (float*)d_out);
    out_mean_kernel<<<Bx, Dx, 0, stream>>>(h, (float*)d_out + (size_t)TOK * Dx);
}

// Round 10
// 2958.908 us; speedup vs baseline: 7.0163x; 1.0486x over previous
//
#include <hip/hip_runtime.h>
#include <hip/hip_bf16.h>

// Problem constants
#define Bx 32
#define Nx 512
#define Dx 512
#define Hx 8
#define DKx 64
#define FFx 2048
#define TOK (Bx * Nx)          // 16384 tokens
#define NBC 8                  // batches per attention chunk
#define EPSx 1e-5f

typedef __bf16 bfrag8 __attribute__((ext_vector_type(8)));
typedef float  f32x4  __attribute__((ext_vector_type(4)));

struct bf2 { __bf16 hi, lo; };
__device__ __forceinline__ bf2 split2(float v) {
    __bf16 h = (__bf16)v;
    bf2 r; r.hi = h; r.lo = (__bf16)(v - (float)h);
    return r;
}

// ---------------------------------------------------------------------------
__device__ __forceinline__ float ldsel(const void* p32, const void* p16, size_t i, int f32) {
    return f32 ? ((const float*)p32)[i]
               : __bfloat162float(((const __hip_bfloat16*)p16)[i]);
}

__global__ void detect_kernel(const void* __restrict__ x, int* __restrict__ flag)
{
    if (threadIdx.x == 0 && blockIdx.x == 0) {
        const unsigned short* u = (const unsigned short*)x;
        int hits = 0;
        for (int i = 0; i < 256; ++i) {
            int e = (u[i] >> 7) & 0xFF;
            if (e >= 0x86) ++hits;
        }
        *flag = (hits > 8) ? 1 : 0;
    }
}

// ---------------------------------------------------------------------------
__global__ __launch_bounds__(256) void embed_kernel(
    const void* __restrict__ x, const void* __restrict__ We,
    const void* __restrict__ be, float* __restrict__ h, const int* __restrict__ dtp)
{
    const int f32 = *dtp;
    size_t idx = (size_t)blockIdx.x * 256 + threadIdx.x;
    int d = idx & (Dx - 1);
    size_t t = idx >> 9;
    float v = ldsel(x, x, t * 2, f32)     * ldsel(We, We, d * 2, f32) +
              ldsel(x, x, t * 2 + 1, f32) * ldsel(We, We, d * 2 + 1, f32) +
              ldsel(be, be, d, f32);
    h[idx] = v;
}

// ---------------------------------------------------------------------------
// Split-bf16 MFMA GEMM, 128x64 tile, BK=32, LDS double-buffer (1 barrier/iter)
// + register prefetch.
// BL: 0 W[n*K+k] (k-contig: W1, W2) ; 2 W[k*N+n] (n-contig: Wo flat)
// EPI: 1 +bias,relu ; 2 +bias(opt)+resid
// ---------------------------------------------------------------------------
template <int BL, int EPI>
__global__ __launch_bounds__(256) void gemm_mfma(
    const float* __restrict__ A,
    const void* __restrict__ W32, const void* __restrict__ W16,
    const void* __restrict__ bias32, const void* __restrict__ bias16,
    const float* __restrict__ resid,
    float* __restrict__ outp, int M, int N, int K, const int* __restrict__ dtp)
{
    const int f32 = *dtp;
    __shared__ __align__(16) __bf16 Ah[2][128][40];
    __shared__ __align__(16) __bf16 Al[2][128][40];
    __shared__ __align__(16) __bf16 Bh[2][64][40];
    __shared__ __align__(16) __bf16 Bl[2][64][40];

    const int tid = threadIdx.x;
    const int bm = blockIdx.y * 128;
    const int bn = blockIdx.x * 64;
    const int lane = tid & 63, wv = tid >> 6;
    const int quad = lane >> 4, lrow = lane & 15;
    const int wm = wv * 32;

    f32x4 acc[2][4] = {};

    const int ar = tid >> 1, akq = (tid & 1) * 16;
    const int br0 = tid >> 2, bkq0 = (tid & 3) * 8;   // BL0
    const int bgk = tid >> 3, bn8 = (tid & 7) * 8;    // BL2

    f32x4 pa[4];
    f32x4 pb[2];

    auto loadA = [&](int k0) {
        const float* ap = A + (size_t)(bm + ar) * K + k0 + akq;
        pa[0] = *(const f32x4*)ap;
        pa[1] = *(const f32x4*)(ap + 4);
        pa[2] = *(const f32x4*)(ap + 8);
        pa[3] = *(const f32x4*)(ap + 12);
    };
    auto loadB = [&](int k0) {
        if constexpr (BL == 0) {
            if (f32) {
                const float* wp = (const float*)W32 + (size_t)(bn + br0) * K + k0 + bkq0;
                pb[0] = *(const f32x4*)wp;
                pb[1] = *(const f32x4*)(wp + 4);
            } else {
                size_t base = (size_t)(bn + br0) * K + k0 + bkq0;
                #pragma unroll
                for (int j = 0; j < 4; ++j) {
                    pb[0][j] = ldsel(W32, W16, base + j, 0);
                    pb[1][j] = ldsel(W32, W16, base + 4 + j, 0);
                }
            }
        } else {
            if (f32) {
                const float* wp = (const float*)W32 + (size_t)(k0 + bgk) * N + bn + bn8;
                pb[0] = *(const f32x4*)wp;
                pb[1] = *(const f32x4*)(wp + 4);
            } else {
                size_t base = (size_t)(k0 + bgk) * N + bn + bn8;
                #pragma unroll
                for (int j = 0; j < 4; ++j) {
                    pb[0][j] = ldsel(W32, W16, base + j, 0);
                    pb[1][j] = ldsel(W32, W16, base + 4 + j, 0);
                }
            }
        }
    };
    auto storeAB = [&](int buf) {
        #pragma unroll
        for (int half = 0; half < 2; ++half) {
            bfrag8 hi, lo;
            #pragma unroll
            for (int j = 0; j < 4; ++j) {
                bf2 s0 = split2(pa[half * 2][j]);     hi[j] = s0.hi;     lo[j] = s0.lo;
                bf2 s1 = split2(pa[half * 2 + 1][j]); hi[j + 4] = s1.hi; lo[j + 4] = s1.lo;
            }
            *(bfrag8*)&Ah[buf][ar][akq + half * 8] = hi;
            *(bfrag8*)&Al[buf][ar][akq + half * 8] = lo;
        }
        if constexpr (BL == 0) {
            bfrag8 hi, lo;
            #pragma unroll
            for (int j = 0; j < 4; ++j) {
                bf2 s0 = split2(pb[0][j]); hi[j] = s0.hi;     lo[j] = s0.lo;
                bf2 s1 = split2(pb[1][j]); hi[j + 4] = s1.hi; lo[j + 4] = s1.lo;
            }
            *(bfrag8*)&Bh[buf][br0][bkq0] = hi;
            *(bfrag8*)&Bl[buf][br0][bkq0] = lo;
        } else {
            #pragma unroll
            for (int j = 0; j < 4; ++j) {
                bf2 s0 = split2(pb[0][j]); Bh[buf][bn8 + j][bgk] = s0.hi;     Bl[buf][bn8 + j][bgk] = s0.lo;
                bf2 s1 = split2(pb[1][j]); Bh[buf][bn8 + 4 + j][bgk] = s1.hi; Bl[buf][bn8 + 4 + j][bgk] = s1.lo;
            }
        }
    };

    loadA(0); loadB(0);
    storeAB(0);
    __syncthreads();

    int cur = 0;
    for (int k0 = 0; k0 < K; k0 += 32) {
        const bool more = (k0 + 32 < K);
        if (more) { loadA(k0 + 32); loadB(k0 + 32); }

        bfrag8 ah[2], alo[2], bh[4], blo[4];
        #pragma unroll
        for (int mt = 0; mt < 2; ++mt) {
            ah[mt]  = *(const bfrag8*)&Ah[cur][wm + mt * 16 + lrow][quad * 8];
            alo[mt] = *(const bfrag8*)&Al[cur][wm + mt * 16 + lrow][quad * 8];
        }
        #pragma unroll
        for (int nt = 0; nt < 4; ++nt) {
            bh[nt]  = *(const bfrag8*)&Bh[cur][nt * 16 + lrow][quad * 8];
            blo[nt] = *(const bfrag8*)&Bl[cur][nt * 16 + lrow][quad * 8];
        }
        #pragma unroll
        for (int mt = 0; mt < 2; ++mt)
            #pragma unroll
            for (int nt = 0; nt < 4; ++nt) {
                acc[mt][nt] = __builtin_amdgcn_mfma_f32_16x16x32_bf16(ah[mt],  bh[nt],  acc[mt][nt], 0, 0, 0);
                acc[mt][nt] = __builtin_amdgcn_mfma_f32_16x16x32_bf16(ah[mt],  blo[nt], acc[mt][nt], 0, 0, 0);
                acc[mt][nt] = __builtin_amdgcn_mfma_f32_16x16x32_bf16(alo[mt], bh[nt],  acc[mt][nt], 0, 0, 0);
            }

        if (more) {
            storeAB(cur ^ 1);
            __syncthreads();
            cur ^= 1;
        }
    }

    #pragma unroll
    for (int mt = 0; mt < 2; ++mt)
        #pragma unroll
        for (int nt = 0; nt < 4; ++nt)
            #pragma unroll
            for (int reg = 0; reg < 4; ++reg) {
                int m = bm + wm + mt * 16 + quad * 4 + reg;
                int n = bn + nt * 16 + lrow;
                float v = acc[mt][nt][reg];
                if constexpr (EPI == 1) { v += ldsel(bias32, bias16, n, f32); v = fmaxf(v, 0.f); }
                if constexpr (EPI == 2) {
                    if (bias32) v += ldsel(bias32, bias16, n, f32);
                    v += resid[(size_t)m * N + n];
                }
                outp[(size_t)m * N + n] = v;
            }
}

// ---------------------------------------------------------------------------
// Fused QKV projection, LDS double-buffer + register prefetch.
// ---------------------------------------------------------------------------
__global__ __launch_bounds__(256) void qkv_mfma(
    const float* __restrict__ A,
    const void* __restrict__ Wq32, const void* __restrict__ Wq16,
    const void* __restrict__ Wk32, const void* __restrict__ Wk16,
    const void* __restrict__ Wv32, const void* __restrict__ Wv16,
    float* __restrict__ Qo, float* __restrict__ Ko, float* __restrict__ Vo,
    int M, int K, const int* __restrict__ dtp)
{
    const int f32 = *dtp;
    __shared__ __align__(16) __bf16 Ah[2][128][40];
    __shared__ __align__(16) __bf16 Al[2][128][40];
    __shared__ __align__(16) __bf16 Bh[2][64][40];
    __shared__ __align__(16) __bf16 Bl[2][64][40];

    const int tid = threadIdx.x;
    const int bm = blockIdx.y * 128;
    const int bn = blockIdx.x * 64;            // 0..1536
    const int sel = bn >> 9;
    const int head = (bn & 511) >> 6;
    const void* W32 = (sel == 0) ? Wq32 : (sel == 1) ? Wk32 : Wv32;
    const void* W16 = (sel == 0) ? Wq16 : (sel == 1) ? Wk16 : Wv16;
    float* outp = (sel == 0) ? Qo : (sel == 1) ? Ko : Vo;

    const int lane = tid & 63, wv = tid >> 6;
    const int quad = lane >> 4, lrow = lane & 15;
    const int wm = wv * 32;

    f32x4 acc[2][4] = {};
    const int ar = tid >> 1, akq = (tid & 1) * 16;
    const int bgk = tid >> 3, bn8 = (tid & 7) * 8;
    const size_t wbase = (size_t)head * K * 64;

    f32x4 pa[4];
    f32x4 pb[2];

    auto loadA = [&](int k0) {
        const float* ap = A + (size_t)(bm + ar) * K + k0 + akq;
        pa[0] = *(const f32x4*)ap;
        pa[1] = *(const f32x4*)(ap + 4);
        pa[2] = *(const f32x4*)(ap + 8);
        pa[3] = *(const f32x4*)(ap + 12);
    };
    auto loadB = [&](int k0) {
        if (f32) {
            const float* wp = (const float*)W32 + wbase + (size_t)(k0 + bgk) * 64 + bn8;
            pb[0] = *(const f32x4*)wp;
            pb[1] = *(const f32x4*)(wp + 4);
        } else {
            size_t base = wbase + (size_t)(k0 + bgk) * 64 + bn8;
            #pragma unroll
            for (int j = 0; j < 4; ++j) {
                pb[0][j] = ldsel(W32, W16, base + j, 0);
                pb[1][j] = ldsel(W32, W16, base + 4 + j, 0);
            }
        }
    };
    auto storeAB = [&](int buf) {
        #pragma unroll
        for (int half = 0; half < 2; ++half) {
            bfrag8 hi, lo;
            #pragma unroll
            for (int j = 0; j < 4; ++j) {
                bf2 s0 = split2(pa[half * 2][j]);     hi[j] = s0.hi;     lo[j] = s0.lo;
                bf2 s1 = split2(pa[half * 2 + 1][j]); hi[j + 4] = s1.hi; lo[j + 4] = s1.lo;
            }
            *(bfrag8*)&Ah[buf][ar][akq + half * 8] = hi;
            *(bfrag8*)&Al[buf][ar][akq + half * 8] = lo;
        }
        #pragma unroll
        for (int j = 0; j < 4; ++j) {
            bf2 s0 = split2(pb[0][j]); Bh[buf][bn8 + j][bgk] = s0.hi;     Bl[buf][bn8 + j][bgk] = s0.lo;
            bf2 s1 = split2(pb[1][j]); Bh[buf][bn8 + 4 + j][bgk] = s1.hi; Bl[buf][bn8 + 4 + j][bgk] = s1.lo;
        }
    };

    loadA(0); loadB(0);
    storeAB(0);
    __syncthreads();

    int cur = 0;
    for (int k0 = 0; k0 < K; k0 += 32) {
        const bool more = (k0 + 32 < K);
        if (more) { loadA(k0 + 32); loadB(k0 + 32); }

        bfrag8 ah[2], alo[2], bh[4], blo[4];
        #pragma unroll
        for (int mt = 0; mt < 2; ++mt) {
            ah[mt]  = *(const bfrag8*)&Ah[cur][wm + mt * 16 + lrow][quad * 8];
            alo[mt] = *(const bfrag8*)&Al[cur][wm + mt * 16 + lrow][quad * 8];
        }
        #pragma unroll
        for (int nt = 0; nt < 4; ++nt) {
            bh[nt]  = *(const bfrag8*)&Bh[cur][nt * 16 + lrow][quad * 8];
            blo[nt] = *(const bfrag8*)&Bl[cur][nt * 16 + lrow][quad * 8];
        }
        #pragma unroll
        for (int mt = 0; mt < 2; ++mt)
            #pragma unroll
            for (int nt = 0; nt < 4; ++nt) {
                acc[mt][nt] = __builtin_amdgcn_mfma_f32_16x16x32_bf16(ah[mt],  bh[nt],  acc[mt][nt], 0, 0, 0);
                acc[mt][nt] = __builtin_amdgcn_mfma_f32_16x16x32_bf16(ah[mt],  blo[nt], acc[mt][nt], 0, 0, 0);
                acc[mt][nt] = __builtin_amdgcn_mfma_f32_16x16x32_bf16(alo[mt], bh[nt],  acc[mt][nt], 0, 0, 0);
            }

        if (more) {
            storeAB(cur ^ 1);
            __syncthreads();
            cur ^= 1;
        }
    }

    const int nb = M >> 9;
    #pragma unroll
    for (int mt = 0; mt < 2; ++mt)
        #pragma unroll
        for (int nt = 0; nt < 4; ++nt)
            #pragma unroll
            for (int reg = 0; reg < 4; ++reg) {
                int m = bm + wm + mt * 16 + quad * 4 + reg;
                int dk = nt * 16 + lrow;
                int b_ = m >> 9, q = m & 511;
                size_t oidx = ((((size_t)head * nb + b_) * Nx + q) * DKx) + dk;
                outp[oidx] = acc[mt][nt][reg];
            }
}

// ---------------------------------------------------------------------------
// MFMA flash attention (unchanged)
// ---------------------------------------------------------------------------
__global__ __launch_bounds__(256) void attn_kernel(
    const float* __restrict__ Q, const float* __restrict__ K,
    const float* __restrict__ V, float* __restrict__ heads, int b0)
{
    __shared__ __align__(16) __bf16 Qh[64][72], Ql[64][72];
    __shared__ __align__(16) __bf16 Kh[64][72], Kl[64][72];
    __shared__ __align__(16) __bf16 Vt[64][72];
    __shared__ __align__(16) __bf16 Pp[64][72];
    __shared__ float Ss[64][66];
    __shared__ float ml[64], ll[64], al[64];

    const int tid = threadIdx.x;
    const int q0 = blockIdx.x * 64;
    const int hb = blockIdx.y;
    const size_t base = (size_t)hb * (Nx * DKx);
    const int lane = tid & 63, wv = tid >> 6;
    const int quad = lane >> 4, lrow = lane & 15;
    const int wm = (wv & 1) * 32, wn = (wv >> 1) * 32;

    {
        const int r = tid >> 2, c16 = (tid & 3) * 16;
        const float* qp = Q + base + (size_t)(q0 + r) * DKx + c16;
        #pragma unroll
        for (int half = 0; half < 2; ++half) {
            f32x4 v0 = *(const f32x4*)(qp + half * 8);
            f32x4 v1 = *(const f32x4*)(qp + half * 8 + 4);
            bfrag8 hi, lo;
            #pragma unroll
            for (int j = 0; j < 4; ++j) {
                bf2 s0 = split2(v0[j]); hi[j] = s0.hi; lo[j] = s0.lo;
                bf2 s1 = split2(v1[j]); hi[j + 4] = s1.hi; lo[j + 4] = s1.lo;
            }
            *(bfrag8*)&Qh[r][c16 + half * 8] = hi;
            *(bfrag8*)&Ql[r][c16 + half * 8] = lo;
        }
    }
    if (tid < 64) { ml[tid] = -INFINITY; ll[tid] = 0.f; }

    f32x4 accO[2][2] = {};

    for (int n0 = 0; n0 < Nx; n0 += 64) {
        __syncthreads();
        {
            const int r = tid >> 2, c16 = (tid & 3) * 16;
            const float* kp = K + base + (size_t)(n0 + r) * DKx + c16;
            #pragma unroll
            for (int half = 0; half < 2; ++half) {
                f32x4 v0 = *(const f32x4*)(kp + half * 8);
                f32x4 v1 = *(const f32x4*)(kp + half * 8 + 4);
                bfrag8 hi, lo;
                #pragma unroll
                for (int j = 0; j < 4; ++j) {
                    bf2 s0 = split2(v0[j]); hi[j] = s0.hi; lo[j] = s0.lo;
                    bf2 s1 = split2(v1[j]); hi[j + 4] = s1.hi; lo[j + 4] = s1.lo;
                }
                *(bfrag8*)&Kh[r][c16 + half * 8] = hi;
                *(bfrag8*)&Kl[r][c16 + half * 8] = lo;
            }
            const float* vp = V + base + (size_t)(n0 + r) * DKx + c16;
            #pragma unroll
            for (int half = 0; half < 2; ++half) {
                f32x4 v0 = *(const f32x4*)(vp + half * 8);
                f32x4 v1 = *(const f32x4*)(vp + half * 8 + 4);
                #pragma unroll
                for (int j = 0; j < 4; ++j) {
                    Vt[c16 + half * 8 + j][r]     = (__bf16)v0[j];
                    Vt[c16 + half * 8 + 4 + j][r] = (__bf16)v1[j];
                }
            }
        }
        __syncthreads();

        f32x4 accS[2][2] = {};
        #pragma unroll
        for (int ks = 0; ks < 2; ++ks) {
            bfrag8 ah[2], alo[2], bh[2], blo[2];
            #pragma unroll
            for (int mt = 0; mt < 2; ++mt) {
                ah[mt]  = *(const bfrag8*)&Qh[wm + mt * 16 + lrow][ks * 32 + quad * 8];
                alo[mt] = *(const bfrag8*)&Ql[wm + mt * 16 + lrow][ks * 32 + quad * 8];
            }
            #pragma unroll
            for (int nt = 0; nt < 2; ++nt) {
                bh[nt]  = *(const bfrag8*)&Kh[wn + nt * 16 + lrow][ks * 32 + quad * 8];
                blo[nt] = *(const bfrag8*)&Kl[wn + nt * 16 + lrow][ks * 32 + quad * 8];
            }
            #pragma unroll
            for (int mt = 0; mt < 2; ++mt)
                #pragma unroll
                for (int nt = 0; nt < 2; ++nt) {
                    accS[mt][nt] = __builtin_amdgcn_mfma_f32_16x16x32_bf16(ah[mt],  bh[nt],  accS[mt][nt], 0, 0, 0);
                    accS[mt][nt] = __builtin_amdgcn_mfma_f32_16x16x32_bf16(ah[mt],  blo[nt], accS[mt][nt], 0, 0, 0);
                    accS[mt][nt] = __builtin_amdgcn_mfma_f32_16x16x32_bf16(alo[mt], bh[nt],  accS[mt][nt], 0, 0, 0);
                }
        }
        #pragma unroll
        for (int mt = 0; mt < 2; ++mt)
            #pragma unroll
            for (int nt = 0; nt < 2; ++nt)
                #pragma unroll
                for (int reg = 0; reg < 4; ++reg)
                    Ss[wm + mt * 16 + quad * 4 + reg][wn + nt * 16 + lrow] = accS[mt][nt][reg] * 0.125f;
        __syncthreads();

        if (tid < 64) {
            float rowmax = -INFINITY;
            #pragma unroll 8
            for (int n = 0; n < 64; ++n) rowmax = fmaxf(rowmax, Ss[tid][n]);
            float mold = ml[tid];
            float mnew = fmaxf(mold, rowmax);
            float alpha = __expf(mold - mnew);
            float sum = 0.f;
            #pragma unroll 8
            for (int n = 0; n < 64; ++n) {
                float p = __expf(Ss[tid][n] - mnew);
                Pp[tid][n] = (__bf16)p;
                sum += p;
            }
            ml[tid] = mnew;
            ll[tid] = ll[tid] * alpha + sum;
            al[tid] = alpha;
        }
        __syncthreads();

        #pragma unroll
        for (int mt = 0; mt < 2; ++mt) {
            float a0 = al[wm + mt * 16 + quad * 4 + 0];
            float a1 = al[wm + mt * 16 + quad * 4 + 1];
            float a2 = al[wm + mt * 16 + quad * 4 + 2];
            float a3 = al[wm + mt * 16 + quad * 4 + 3];
            #pragma unroll
            for (int nt = 0; nt < 2; ++nt) {
                accO[mt][nt][0] *= a0; accO[mt][nt][1] *= a1;
                accO[mt][nt][2] *= a2; accO[mt][nt][3] *= a3;
            }
        }
        #pragma unroll
        for (int ks = 0; ks < 2; ++ks) {
            bfrag8 ap[2], bv[2];
            #pragma unroll
            for (int mt = 0; mt < 2; ++mt)
                ap[mt] = *(const bfrag8*)&Pp[wm + mt * 16 + lrow][ks * 32 + quad * 8];
            #pragma unroll
            for (int nt = 0; nt < 2; ++nt)
                bv[nt] = *(const bfrag8*)&Vt[wn + nt * 16 + lrow][ks * 32 + quad * 8];
            #pragma unroll
            for (int mt = 0; mt < 2; ++mt)
                #pragma unroll
                for (int nt = 0; nt < 2; ++nt)
                    accO[mt][nt] = __builtin_amdgcn_mfma_f32_16x16x32_bf16(ap[mt], bv[nt], accO[mt][nt], 0, 0, 0);
        }
    }
    __syncthreads();

    const int h_ = hb / NBC, b_ = hb % NBC;
    #pragma unroll
    for (int mt = 0; mt < 2; ++mt)
        #pragma unroll
        for (int reg = 0; reg < 4; ++reg) {
            int qrow = wm + mt * 16 + quad * 4 + reg;
            float invl = 1.f / ll[qrow];
            size_t tok = (size_t)(b0 + b_) * Nx + (q0 + qrow);
            #pragma unroll
            for (int nt = 0; nt < 2; ++nt) {
                int dk = wn + nt * 16 + lrow;
                heads[tok * Dx + h_ * DKx + dk] = accO[mt][nt][reg] * invl;
            }
        }
}

// ---------------------------------------------------------------------------
__global__ __launch_bounds__(256) void bn_stats(const float* __restrict__ t, float* __restrict__ stats)
{
    int r0 = blockIdx.x * 64;
    int c = threadIdx.x;
    float s0 = 0, q0 = 0, s1 = 0, q1 = 0;
    for (int r = 0; r < 64; ++r) {
        const float* row = t + (size_t)(r0 + r) * Dx;
        float v0 = row[c], v1 = row[c + 256];
        s0 += v0; q0 += v0 * v0; s1 += v1; q1 += v1 * v1;
    }
    atomicAdd(&stats[c], s0);
    atomicAdd(&stats[c + 256], s1);
    atomicAdd(&stats[Dx + c], q0);
    atomicAdd(&stats[Dx + c + 256], q1);
}

__global__ __launch_bounds__(256) void bn_norm(
    const float* __restrict__ t, const float* __restrict__ stats,
    const void* __restrict__ g32, const void* __restrict__ g16,
    const void* __restrict__ b32, const void* __restrict__ b16,
    float* __restrict__ h, const int* __restrict__ dtp)
{
    const int f32 = *dtp;
    size_t idx = (size_t)blockIdx.x * 256 + threadIdx.x;
    int c = idx & (Dx - 1);
    const float invM = 1.f / (float)TOK;
    float mu = stats[c] * invM;
    float var = stats[Dx + c] * invM - mu * mu;
    float v = (t[idx] - mu) * rsqrtf(var + EPSx) * ldsel(g32, g16, c, f32) + ldsel(b32, b16, c, f32);
    h[idx] = v;
}

// ---------------------------------------------------------------------------
__global__ __launch_bounds__(256) void out_h_kernel(const float* __restrict__ h, float* __restrict__ out)
{
    size_t idx = (size_t)blockIdx.x * 256 + threadIdx.x;
    out[idx] = h[idx];
}

__global__ __launch_bounds__(512) void out_mean_kernel(const float* __restrict__ h, float* __restrict__ out2)
{
    int b = blockIdx.x;
    int d = threadIdx.x;
    float s = 0.f;
    for (int n = 0; n < Nx; ++n) s += h[((size_t)b * Nx + n) * Dx + d];
    out2[b * Dx + d] = s * (1.f / (float)Nx);
}

// ---------------------------------------------------------------------------
extern "C" void kernel_launch(void* const* d_in, const int* in_sizes, int n_in,
                              void* d_out, int out_size, void* d_ws, size_t ws_size,
                              hipStream_t stream)
{
    const void* x   = d_in[0];
    const void* We  = d_in[1];
    const void* be  = d_in[2];
    const void* Wq  = d_in[3];
    const void* Wk  = d_in[4];
    const void* Wv  = d_in[5];
    const void* Wo  = d_in[6];
    const void* g1  = d_in[7];
    const void* b1  = d_in[8];
    const void* W1  = d_in[9];
    const void* bb1 = d_in[10];
    const void* W2  = d_in[11];
    const void* bb2 = d_in[12];
    const void* g2  = d_in[13];
    const void* b2  = d_in[14];

    const size_t szWqkv = (size_t)Hx * Dx * DKx;
    const size_t szWo   = (size_t)Hx * DKx * Dx;
    const size_t szW1   = (size_t)FFx * Dx;
    const size_t szW2   = (size_t)Dx * FFx;

    // workspace layout: h | t | stats/dtp | region (attention bufs OR ffbuf)
    float* h     = (float*)d_ws;                       // 32 MB
    float* t     = h + (size_t)TOK * Dx;               // 32 MB
    float* stats = t + (size_t)TOK * Dx;               // 4 KB
    int*   dtp   = (int*)(stats + 2 * Dx);
    float* region = stats + 2 * Dx + 64;
    // attention-phase views
    const size_t CH = (size_t)Hx * NBC * Nx * DKx;     // 2,097,152 floats
    float* heads = region;                             // 32 MB
    float* Qb    = heads + (size_t)TOK * Dx;
    float* Kb    = Qb + CH;
    float* Vb    = Kb + CH;
    // FF-phase view (overlaps heads/QKV)
    float* ffbuf = region;

    // choose FF token-chunk size from available workspace (constant across calls)
    const size_t regionOff = (size_t)(region - (float*)d_ws);
    const size_t availF = (ws_size / 4 > regionOff) ? (ws_size / 4 - regionOff) : 0;
    int ffTok;
    if      (availF >= (size_t)TOK * FFx)  ffTok = TOK;    // 128 MB ffbuf, grid 4/CU
    else if (availF >= (size_t)8192 * FFx) ffTok = 8192;   // 64 MB, 2/CU
    else                                   ffTok = 4096;   // 32 MB, 1/CU (fallback)
    const int nFF = TOK / ffTok;

    auto p32 = [](const void* p, size_t e) { return (const void*)((const float*)p + e); };
    auto p16 = [](const void* p, size_t e) { return (const void*)((const __hip_bfloat16*)p + e); };

    detect_kernel<<<1, 64, 0, stream>>>(x, dtp);
    embed_kernel<<<TOK * Dx / 256, 256, 0, stream>>>(x, We, be, h, dtp);

    const int chTok = NBC * Nx;                       // 4096
    const dim3 gQKV(24, chTok / 128);                 // (24, 32)
    const dim3 gWo(Dx / 64, TOK / 128);               // (8, 128)
    const dim3 gAttn(Nx / 64, Hx * NBC);              // (8, 64)
    for (int l = 0; l < 3; ++l) {
        const size_t eW = (size_t)l * szWqkv, eO = (size_t)l * szWo;
        const size_t e1 = (size_t)l * szW1,  e2 = (size_t)l * szW2;
        const size_t eD = (size_t)l * Dx,    eF = (size_t)l * FFx;

        for (int ch = 0; ch < 4; ++ch) {
            const float* hc = h + (size_t)ch * chTok * Dx;
            qkv_mfma<<<gQKV, 256, 0, stream>>>(
                hc, p32(Wq, eW), p16(Wq, eW), p32(Wk, eW), p16(Wk, eW),
                p32(Wv, eW), p16(Wv, eW), Qb, Kb, Vb, chTok, Dx, dtp);
            attn_kernel<<<gAttn, 256, 0, stream>>>(Qb, Kb, Vb, heads, ch * NBC);
        }

        // output projection + residual: t = h + heads @ Wo_flat
        gemm_mfma<2, 2><<<gWo, 256, 0, stream>>>(
            heads, p32(Wo, eO), p16(Wo, eO), nullptr, nullptr, h, t, TOK, Dx, Dx, dtp);

        hipMemsetAsync(stats, 0, 2 * Dx * sizeof(float), stream);
        bn_stats<<<256, 256, 0, stream>>>(t, stats);
        bn_norm<<<TOK * Dx / 256, 256, 0, stream>>>(
            t, stats, p32(g1, eD), p16(g1, eD), p32(b1, eD), p16(b1, eD), h, dtp);

        // FF in nFF chunks of ffTok tokens
        for (int ch = 0; ch < nFF; ++ch) {
            float* hc = h + (size_t)ch * ffTok * Dx;
            float* tc = t + (size_t)ch * ffTok * Dx;
            gemm_mfma<0, 1><<<dim3(FFx / 64, ffTok / 128), 256, 0, stream>>>(
                hc, p32(W1, e1), p16(W1, e1), p32(bb1, eF), p16(bb1, eF), nullptr, ffbuf, ffTok, FFx, Dx, dtp);
            gemm_mfma<0, 2><<<dim3(Dx / 64, ffTok / 128), 256, 0, stream>>>(
                ffbuf, p32(W2, e2), p16(W2, e2), p32(bb2, eD), p16(bb2, eD), hc, tc, ffTok, Dx, FFx, dtp);
        }

        hipMemsetAsync(stats, 0, 2 * Dx * sizeof(float), stream);
        bn_stats<<<256, 256, 0, stream>>>(t, stats);
        bn_norm<<<TOK * Dx / 256, 256, 0, stream>>>(
            t, stats, p32(g2, eD), p16(g2, eD), p32(b2, eD), p16(b2, eD), h, dtp);
    }

    out_h_kernel<<<TOK * Dx / 256, 256, 0, stream>>>(h, (float*)d_out);
    out_mean_kernel<<<Bx, Dx, 0, stream>>>(h, (float*)d_out + (size_t)TOK * Dx);
}

// Round 11
// 2586.174 us; speedup vs baseline: 8.0276x; 1.1441x over previous
//
#include <hip/hip_runtime.h>
#include <hip/hip_bf16.h>

// Problem constants
#define Bx 32
#define Nx 512
#define Dx 512
#define Hx 8
#define DKx 64
#define FFx 2048
#define TOK (Bx * Nx)          // 16384 tokens
#define EPSx 1e-5f

typedef __bf16 bfrag8 __attribute__((ext_vector_type(8)));
typedef float  f32x4  __attribute__((ext_vector_type(4)));

struct bf2 { __bf16 hi, lo; };
__device__ __forceinline__ bf2 split2(float v) {
    __bf16 h = (__bf16)v;
    bf2 r; r.hi = h; r.lo = (__bf16)(v - (float)h);
    return r;
}

// ---------------------------------------------------------------------------
__device__ __forceinline__ float ldsel(const void* p32, const void* p16, size_t i, int f32) {
    return f32 ? ((const float*)p32)[i]
               : __bfloat162float(((const __hip_bfloat16*)p16)[i]);
}

__global__ void detect_kernel(const void* __restrict__ x, int* __restrict__ flag)
{
    if (threadIdx.x == 0 && blockIdx.x == 0) {
        const unsigned short* u = (const unsigned short*)x;
        int hits = 0;
        for (int i = 0; i < 256; ++i) {
            int e = (u[i] >> 7) & 0xFF;
            if (e >= 0x86) ++hits;
        }
        *flag = (hits > 8) ? 1 : 0;
    }
}

// ---------------------------------------------------------------------------
__global__ __launch_bounds__(256) void embed_kernel(
    const void* __restrict__ x, const void* __restrict__ We,
    const void* __restrict__ be, float* __restrict__ h, const int* __restrict__ dtp)
{
    const int f32 = *dtp;
    size_t idx = (size_t)blockIdx.x * 256 + threadIdx.x;
    int d = idx & (Dx - 1);
    size_t t = idx >> 9;
    float v = ldsel(x, x, t * 2, f32)     * ldsel(We, We, d * 2, f32) +
              ldsel(x, x, t * 2 + 1, f32) * ldsel(We, We, d * 2 + 1, f32) +
              ldsel(be, be, d, f32);
    h[idx] = v;
}

// ---------------------------------------------------------------------------
// Split-bf16 MFMA GEMM, 128x64 tile, BK=32, LDS double-buffer + reg prefetch.
// BL: 0 W[n*K+k] (k-contig: W1, W2) ; 2 W[k*N+n] (n-contig: Wo flat)
// EPI: 1 +bias,relu ; 2 +bias(opt)+resid
// A16: A is bf16 row-major (no lo plane, 2 MFMAs/tile) ; else fp32 split (3)
// OBF: output bf16 ; else fp32
// ---------------------------------------------------------------------------
template <int BL, int EPI, int A16, int OBF>
__global__ __launch_bounds__(256) void gemm_mfma(
    const void* __restrict__ A,
    const void* __restrict__ W32, const void* __restrict__ W16,
    const void* __restrict__ bias32, const void* __restrict__ bias16,
    const float* __restrict__ resid,
    void* __restrict__ outp, int M, int N, int K, const int* __restrict__ dtp)
{
    const int f32 = *dtp;
    __shared__ __align__(16) __bf16 Ah[2][128][40];
    __shared__ __align__(16) __bf16 Al[A16 ? 1 : 2][A16 ? 1 : 128][A16 ? 8 : 40];
    __shared__ __align__(16) __bf16 Bh[2][64][40];
    __shared__ __align__(16) __bf16 Bl[2][64][40];

    const int tid = threadIdx.x;
    const int bm = blockIdx.y * 128;
    const int bn = blockIdx.x * 64;
    const int lane = tid & 63, wv = tid >> 6;
    const int quad = lane >> 4, lrow = lane & 15;
    const int wm = wv * 32;

    f32x4 acc[2][4] = {};

    const int ar = tid >> 1, akq = (tid & 1) * 16;
    const int br0 = tid >> 2, bkq0 = (tid & 3) * 8;   // BL0
    const int bgk = tid >> 3, bn8 = (tid & 7) * 8;    // BL2

    f32x4 pa[4];
    bfrag8 pa16[2];
    f32x4 pb[2];

    auto loadA = [&](int k0) {
        if constexpr (A16) {
            const __bf16* ap = (const __bf16*)A + (size_t)(bm + ar) * K + k0 + akq;
            pa16[0] = *(const bfrag8*)ap;
            pa16[1] = *(const bfrag8*)(ap + 8);
        } else {
            const float* ap = (const float*)A + (size_t)(bm + ar) * K + k0 + akq;
            pa[0] = *(const f32x4*)ap;
            pa[1] = *(const f32x4*)(ap + 4);
            pa[2] = *(const f32x4*)(ap + 8);
            pa[3] = *(const f32x4*)(ap + 12);
        }
    };
    auto loadB = [&](int k0) {
        if constexpr (BL == 0) {
            if (f32) {
                const float* wp = (const float*)W32 + (size_t)(bn + br0) * K + k0 + bkq0;
                pb[0] = *(const f32x4*)wp;
                pb[1] = *(const f32x4*)(wp + 4);
            } else {
                size_t base = (size_t)(bn + br0) * K + k0 + bkq0;
                #pragma unroll
                for (int j = 0; j < 4; ++j) {
                    pb[0][j] = ldsel(W32, W16, base + j, 0);
                    pb[1][j] = ldsel(W32, W16, base + 4 + j, 0);
                }
            }
        } else {
            if (f32) {
                const float* wp = (const float*)W32 + (size_t)(k0 + bgk) * N + bn + bn8;
                pb[0] = *(const f32x4*)wp;
                pb[1] = *(const f32x4*)(wp + 4);
            } else {
                size_t base = (size_t)(k0 + bgk) * N + bn + bn8;
                #pragma unroll
                for (int j = 0; j < 4; ++j) {
                    pb[0][j] = ldsel(W32, W16, base + j, 0);
                    pb[1][j] = ldsel(W32, W16, base + 4 + j, 0);
                }
            }
        }
    };
    auto storeAB = [&](int buf) {
        if constexpr (A16) {
            *(bfrag8*)&Ah[buf][ar][akq]     = pa16[0];
            *(bfrag8*)&Ah[buf][ar][akq + 8] = pa16[1];
        } else {
            #pragma unroll
            for (int half = 0; half < 2; ++half) {
                bfrag8 hi, lo;
                #pragma unroll
                for (int j = 0; j < 4; ++j) {
                    bf2 s0 = split2(pa[half * 2][j]);     hi[j] = s0.hi;     lo[j] = s0.lo;
                    bf2 s1 = split2(pa[half * 2 + 1][j]); hi[j + 4] = s1.hi; lo[j + 4] = s1.lo;
                }
                *(bfrag8*)&Ah[buf][ar][akq + half * 8] = hi;
                *(bfrag8*)&Al[buf][ar][akq + half * 8] = lo;
            }
        }
        if constexpr (BL == 0) {
            bfrag8 hi, lo;
            #pragma unroll
            for (int j = 0; j < 4; ++j) {
                bf2 s0 = split2(pb[0][j]); hi[j] = s0.hi;     lo[j] = s0.lo;
                bf2 s1 = split2(pb[1][j]); hi[j + 4] = s1.hi; lo[j + 4] = s1.lo;
            }
            *(bfrag8*)&Bh[buf][br0][bkq0] = hi;
            *(bfrag8*)&Bl[buf][br0][bkq0] = lo;
        } else {
            #pragma unroll
            for (int j = 0; j < 4; ++j) {
                bf2 s0 = split2(pb[0][j]); Bh[buf][bn8 + j][bgk] = s0.hi;     Bl[buf][bn8 + j][bgk] = s0.lo;
                bf2 s1 = split2(pb[1][j]); Bh[buf][bn8 + 4 + j][bgk] = s1.hi; Bl[buf][bn8 + 4 + j][bgk] = s1.lo;
            }
        }
    };

    loadA(0); loadB(0);
    storeAB(0);
    __syncthreads();

    int cur = 0;
    for (int k0 = 0; k0 < K; k0 += 32) {
        const bool more = (k0 + 32 < K);
        if (more) { loadA(k0 + 32); loadB(k0 + 32); }

        bfrag8 ah[2], alo[2], bh[4], blo[4];
        #pragma unroll
        for (int mt = 0; mt < 2; ++mt) {
            ah[mt] = *(const bfrag8*)&Ah[cur][wm + mt * 16 + lrow][quad * 8];
            if constexpr (!A16) alo[mt] = *(const bfrag8*)&Al[cur][wm + mt * 16 + lrow][quad * 8];
        }
        #pragma unroll
        for (int nt = 0; nt < 4; ++nt) {
            bh[nt]  = *(const bfrag8*)&Bh[cur][nt * 16 + lrow][quad * 8];
            blo[nt] = *(const bfrag8*)&Bl[cur][nt * 16 + lrow][quad * 8];
        }
        #pragma unroll
        for (int mt = 0; mt < 2; ++mt)
            #pragma unroll
            for (int nt = 0; nt < 4; ++nt) {
                acc[mt][nt] = __builtin_amdgcn_mfma_f32_16x16x32_bf16(ah[mt], bh[nt],  acc[mt][nt], 0, 0, 0);
                acc[mt][nt] = __builtin_amdgcn_mfma_f32_16x16x32_bf16(ah[mt], blo[nt], acc[mt][nt], 0, 0, 0);
                if constexpr (!A16)
                    acc[mt][nt] = __builtin_amdgcn_mfma_f32_16x16x32_bf16(alo[mt], bh[nt], acc[mt][nt], 0, 0, 0);
            }

        if (more) {
            storeAB(cur ^ 1);
            __syncthreads();
            cur ^= 1;
        }
    }

    #pragma unroll
    for (int mt = 0; mt < 2; ++mt)
        #pragma unroll
        for (int nt = 0; nt < 4; ++nt)
            #pragma unroll
            for (int reg = 0; reg < 4; ++reg) {
                int m = bm + wm + mt * 16 + quad * 4 + reg;
                int n = bn + nt * 16 + lrow;
                float v = acc[mt][nt][reg];
                if constexpr (EPI == 1) { v += ldsel(bias32, bias16, n, f32); v = fmaxf(v, 0.f); }
                if constexpr (EPI == 2) {
                    if (bias32) v += ldsel(bias32, bias16, n, f32);
                    v += resid[(size_t)m * N + n];
                }
                if constexpr (OBF) ((__bf16*)outp)[(size_t)m * N + n] = (__bf16)v;
                else               ((float*)outp)[(size_t)m * N + n] = v;
            }
}

// ---------------------------------------------------------------------------
// Fused QKV projection (full batch): N=1536; Q,K fp32 ; V bf16.
// Scatter to [H, B, N, DK].
// ---------------------------------------------------------------------------
__global__ __launch_bounds__(256) void qkv_mfma(
    const float* __restrict__ A,
    const void* __restrict__ Wq32, const void* __restrict__ Wq16,
    const void* __restrict__ Wk32, const void* __restrict__ Wk16,
    const void* __restrict__ Wv32, const void* __restrict__ Wv16,
    float* __restrict__ Qo, float* __restrict__ Ko, __bf16* __restrict__ Vo,
    int M, int K, const int* __restrict__ dtp)
{
    const int f32 = *dtp;
    __shared__ __align__(16) __bf16 Ah[2][128][40];
    __shared__ __align__(16) __bf16 Al[2][128][40];
    __shared__ __align__(16) __bf16 Bh[2][64][40];
    __shared__ __align__(16) __bf16 Bl[2][64][40];

    const int tid = threadIdx.x;
    const int bm = blockIdx.y * 128;
    const int bn = blockIdx.x * 64;            // 0..1536
    const int sel = bn >> 9;
    const int head = (bn & 511) >> 6;
    const void* W32 = (sel == 0) ? Wq32 : (sel == 1) ? Wk32 : Wv32;
    const void* W16 = (sel == 0) ? Wq16 : (sel == 1) ? Wk16 : Wv16;

    const int lane = tid & 63, wv = tid >> 6;
    const int quad = lane >> 4, lrow = lane & 15;
    const int wm = wv * 32;

    f32x4 acc[2][4] = {};
    const int ar = tid >> 1, akq = (tid & 1) * 16;
    const int bgk = tid >> 3, bn8 = (tid & 7) * 8;
    const size_t wbase = (size_t)head * K * 64;

    f32x4 pa[4];
    f32x4 pb[2];

    auto loadA = [&](int k0) {
        const float* ap = A + (size_t)(bm + ar) * K + k0 + akq;
        pa[0] = *(const f32x4*)ap;
        pa[1] = *(const f32x4*)(ap + 4);
        pa[2] = *(const f32x4*)(ap + 8);
        pa[3] = *(const f32x4*)(ap + 12);
    };
    auto loadB = [&](int k0) {
        if (f32) {
            const float* wp = (const float*)W32 + wbase + (size_t)(k0 + bgk) * 64 + bn8;
            pb[0] = *(const f32x4*)wp;
            pb[1] = *(const f32x4*)(wp + 4);
        } else {
            size_t base = wbase + (size_t)(k0 + bgk) * 64 + bn8;
            #pragma unroll
            for (int j = 0; j < 4; ++j) {
                pb[0][j] = ldsel(W32, W16, base + j, 0);
                pb[1][j] = ldsel(W32, W16, base + 4 + j, 0);
            }
        }
    };
    auto storeAB = [&](int buf) {
        #pragma unroll
        for (int half = 0; half < 2; ++half) {
            bfrag8 hi, lo;
            #pragma unroll
            for (int j = 0; j < 4; ++j) {
                bf2 s0 = split2(pa[half * 2][j]);     hi[j] = s0.hi;     lo[j] = s0.lo;
                bf2 s1 = split2(pa[half * 2 + 1][j]); hi[j + 4] = s1.hi; lo[j + 4] = s1.lo;
            }
            *(bfrag8*)&Ah[buf][ar][akq + half * 8] = hi;
            *(bfrag8*)&Al[buf][ar][akq + half * 8] = lo;
        }
        #pragma unroll
        for (int j = 0; j < 4; ++j) {
            bf2 s0 = split2(pb[0][j]); Bh[buf][bn8 + j][bgk] = s0.hi;     Bl[buf][bn8 + j][bgk] = s0.lo;
            bf2 s1 = split2(pb[1][j]); Bh[buf][bn8 + 4 + j][bgk] = s1.hi; Bl[buf][bn8 + 4 + j][bgk] = s1.lo;
        }
    };

    loadA(0); loadB(0);
    storeAB(0);
    __syncthreads();

    int cur = 0;
    for (int k0 = 0; k0 < K; k0 += 32) {
        const bool more = (k0 + 32 < K);
        if (more) { loadA(k0 + 32); loadB(k0 + 32); }

        bfrag8 ah[2], alo[2], bh[4], blo[4];
        #pragma unroll
        for (int mt = 0; mt < 2; ++mt) {
            ah[mt]  = *(const bfrag8*)&Ah[cur][wm + mt * 16 + lrow][quad * 8];
            alo[mt] = *(const bfrag8*)&Al[cur][wm + mt * 16 + lrow][quad * 8];
        }
        #pragma unroll
        for (int nt = 0; nt < 4; ++nt) {
            bh[nt]  = *(const bfrag8*)&Bh[cur][nt * 16 + lrow][quad * 8];
            blo[nt] = *(const bfrag8*)&Bl[cur][nt * 16 + lrow][quad * 8];
        }
        #pragma unroll
        for (int mt = 0; mt < 2; ++mt)
            #pragma unroll
            for (int nt = 0; nt < 4; ++nt) {
                acc[mt][nt] = __builtin_amdgcn_mfma_f32_16x16x32_bf16(ah[mt],  bh[nt],  acc[mt][nt], 0, 0, 0);
                acc[mt][nt] = __builtin_amdgcn_mfma_f32_16x16x32_bf16(ah[mt],  blo[nt], acc[mt][nt], 0, 0, 0);
                acc[mt][nt] = __builtin_amdgcn_mfma_f32_16x16x32_bf16(alo[mt], bh[nt],  acc[mt][nt], 0, 0, 0);
            }

        if (more) {
            storeAB(cur ^ 1);
            __syncthreads();
            cur ^= 1;
        }
    }

    const int nb = M >> 9;   // batches (32)
    #pragma unroll
    for (int mt = 0; mt < 2; ++mt)
        #pragma unroll
        for (int nt = 0; nt < 4; ++nt)
            #pragma unroll
            for (int reg = 0; reg < 4; ++reg) {
                int m = bm + wm + mt * 16 + quad * 4 + reg;
                int dk = nt * 16 + lrow;
                int b_ = m >> 9, q = m & 511;
                size_t oidx = ((((size_t)head * nb + b_) * Nx + q) * DKx) + dk;
                if (sel == 2) Vo[oidx] = (__bf16)acc[mt][nt][reg];
                else if (sel == 1) Ko[oidx] = acc[mt][nt][reg];
                else Qo[oidx] = acc[mt][nt][reg];
            }
}

// ---------------------------------------------------------------------------
// MFMA flash attention (full batch): Q,K fp32 [H,B,N,DK] split; V bf16.
// ---------------------------------------------------------------------------
__global__ __launch_bounds__(256) void attn_kernel(
    const float* __restrict__ Q, const float* __restrict__ K,
    const __bf16* __restrict__ V, float* __restrict__ heads)
{
    __shared__ __align__(16) __bf16 Qh[64][72], Ql[64][72];
    __shared__ __align__(16) __bf16 Kh[64][72], Kl[64][72];
    __shared__ __align__(16) __bf16 Vt[64][72];
    __shared__ __align__(16) __bf16 Pp[64][72];
    __shared__ float Ss[64][66];
    __shared__ float ml[64], ll[64], al[64];

    const int tid = threadIdx.x;
    const int q0 = blockIdx.x * 64;
    const int hb = blockIdx.y;                 // h*Bx + b
    const size_t base = (size_t)hb * (Nx * DKx);
    const int lane = tid & 63, wv = tid >> 6;
    const int quad = lane >> 4, lrow = lane & 15;
    const int wm = (wv & 1) * 32, wn = (wv >> 1) * 32;

    {
        const int r = tid >> 2, c16 = (tid & 3) * 16;
        const float* qp = Q + base + (size_t)(q0 + r) * DKx + c16;
        #pragma unroll
        for (int half = 0; half < 2; ++half) {
            f32x4 v0 = *(const f32x4*)(qp + half * 8);
            f32x4 v1 = *(const f32x4*)(qp + half * 8 + 4);
            bfrag8 hi, lo;
            #pragma unroll
            for (int j = 0; j < 4; ++j) {
                bf2 s0 = split2(v0[j]); hi[j] = s0.hi; lo[j] = s0.lo;
                bf2 s1 = split2(v1[j]); hi[j + 4] = s1.hi; lo[j + 4] = s1.lo;
            }
            *(bfrag8*)&Qh[r][c16 + half * 8] = hi;
            *(bfrag8*)&Ql[r][c16 + half * 8] = lo;
        }
    }
    if (tid < 64) { ml[tid] = -INFINITY; ll[tid] = 0.f; }

    f32x4 accO[2][2] = {};

    for (int n0 = 0; n0 < Nx; n0 += 64) {
        __syncthreads();
        {
            const int r = tid >> 2, c16 = (tid & 3) * 16;
            const float* kp = K + base + (size_t)(n0 + r) * DKx + c16;
            #pragma unroll
            for (int half = 0; half < 2; ++half) {
                f32x4 v0 = *(const f32x4*)(kp + half * 8);
                f32x4 v1 = *(const f32x4*)(kp + half * 8 + 4);
                bfrag8 hi, lo;
                #pragma unroll
                for (int j = 0; j < 4; ++j) {
                    bf2 s0 = split2(v0[j]); hi[j] = s0.hi; lo[j] = s0.lo;
                    bf2 s1 = split2(v1[j]); hi[j + 4] = s1.hi; lo[j + 4] = s1.lo;
                }
                *(bfrag8*)&Kh[r][c16 + half * 8] = hi;
                *(bfrag8*)&Kl[r][c16 + half * 8] = lo;
            }
            const __bf16* vp = V + base + (size_t)(n0 + r) * DKx + c16;
            bfrag8 v0 = *(const bfrag8*)vp;
            bfrag8 v1 = *(const bfrag8*)(vp + 8);
            #pragma unroll
            for (int j = 0; j < 8; ++j) {
                Vt[c16 + j][r]     = v0[j];
                Vt[c16 + 8 + j][r] = v1[j];
            }
        }
        __syncthreads();

        f32x4 accS[2][2] = {};
        #pragma unroll
        for (int ks = 0; ks < 2; ++ks) {
            bfrag8 ah[2], alo[2], bh[2], blo[2];
            #pragma unroll
            for (int mt = 0; mt < 2; ++mt) {
                ah[mt]  = *(const bfrag8*)&Qh[wm + mt * 16 + lrow][ks * 32 + quad * 8];
                alo[mt] = *(const bfrag8*)&Ql[wm + mt * 16 + lrow][ks * 32 + quad * 8];
            }
            #pragma unroll
            for (int nt = 0; nt < 2; ++nt) {
                bh[nt]  = *(const bfrag8*)&Kh[wn + nt * 16 + lrow][ks * 32 + quad * 8];
                blo[nt] = *(const bfrag8*)&Kl[wn + nt * 16 + lrow][ks * 32 + quad * 8];
            }
            #pragma unroll
            for (int mt = 0; mt < 2; ++mt)
                #pragma unroll
                for (int nt = 0; nt < 2; ++nt) {
                    accS[mt][nt] = __builtin_amdgcn_mfma_f32_16x16x32_bf16(ah[mt],  bh[nt],  accS[mt][nt], 0, 0, 0);
                    accS[mt][nt] = __builtin_amdgcn_mfma_f32_16x16x32_bf16(ah[mt],  blo[nt], accS[mt][nt], 0, 0, 0);
                    accS[mt][nt] = __builtin_amdgcn_mfma_f32_16x16x32_bf16(alo[mt], bh[nt],  accS[mt][nt], 0, 0, 0);
                }
        }
        #pragma unroll
        for (int mt = 0; mt < 2; ++mt)
            #pragma unroll
            for (int nt = 0; nt < 2; ++nt)
                #pragma unroll
                for (int reg = 0; reg < 4; ++reg)
                    Ss[wm + mt * 16 + quad * 4 + reg][wn + nt * 16 + lrow] = accS[mt][nt][reg] * 0.125f;
        __syncthreads();

        if (tid < 64) {
            float rowmax = -INFINITY;
            #pragma unroll 8
            for (int n = 0; n < 64; ++n) rowmax = fmaxf(rowmax, Ss[tid][n]);
            float mold = ml[tid];
            float mnew = fmaxf(mold, rowmax);
            float alpha = __expf(mold - mnew);
            float sum = 0.f;
            #pragma unroll 8
            for (int n = 0; n < 64; ++n) {
                float p = __expf(Ss[tid][n] - mnew);
                Pp[tid][n] = (__bf16)p;
                sum += p;
            }
            ml[tid] = mnew;
            ll[tid] = ll[tid] * alpha + sum;
            al[tid] = alpha;
        }
        __syncthreads();

        #pragma unroll
        for (int mt = 0; mt < 2; ++mt) {
            float a0 = al[wm + mt * 16 + quad * 4 + 0];
            float a1 = al[wm + mt * 16 + quad * 4 + 1];
            float a2 = al[wm + mt * 16 + quad * 4 + 2];
            float a3 = al[wm + mt * 16 + quad * 4 + 3];
            #pragma unroll
            for (int nt = 0; nt < 2; ++nt) {
                accO[mt][nt][0] *= a0; accO[mt][nt][1] *= a1;
                accO[mt][nt][2] *= a2; accO[mt][nt][3] *= a3;
            }
        }
        #pragma unroll
        for (int ks = 0; ks < 2; ++ks) {
            bfrag8 ap[2], bv[2];
            #pragma unroll
            for (int mt = 0; mt < 2; ++mt)
                ap[mt] = *(const bfrag8*)&Pp[wm + mt * 16 + lrow][ks * 32 + quad * 8];
            #pragma unroll
            for (int nt = 0; nt < 2; ++nt)
                bv[nt] = *(const bfrag8*)&Vt[wn + nt * 16 + lrow][ks * 32 + quad * 8];
            #pragma unroll
            for (int mt = 0; mt < 2; ++mt)
                #pragma unroll
                for (int nt = 0; nt < 2; ++nt)
                    accO[mt][nt] = __builtin_amdgcn_mfma_f32_16x16x32_bf16(ap[mt], bv[nt], accO[mt][nt], 0, 0, 0);
        }
    }
    __syncthreads();

    const int h_ = hb >> 5, b_ = hb & 31;
    #pragma unroll
    for (int mt = 0; mt < 2; ++mt)
        #pragma unroll
        for (int reg = 0; reg < 4; ++reg) {
            int qrow = wm + mt * 16 + quad * 4 + reg;
            float invl = 1.f / ll[qrow];
            size_t tok = (size_t)b_ * Nx + (q0 + qrow);
            #pragma unroll
            for (int nt = 0; nt < 2; ++nt) {
                int dk = wn + nt * 16 + lrow;
                heads[tok * Dx + h_ * DKx + dk] = accO[mt][nt][reg] * invl;
            }
        }
}

// ---------------------------------------------------------------------------
__global__ __launch_bounds__(256) void bn_stats(const float* __restrict__ t, float* __restrict__ stats)
{
    int r0 = blockIdx.x * 64;
    int c = threadIdx.x;
    float s0 = 0, q0 = 0, s1 = 0, q1 = 0;
    for (int r = 0; r < 64; ++r) {
        const float* row = t + (size_t)(r0 + r) * Dx;
        float v0 = row[c], v1 = row[c + 256];
        s0 += v0; q0 += v0 * v0; s1 += v1; q1 += v1 * v1;
    }
    atomicAdd(&stats[c], s0);
    atomicAdd(&stats[c + 256], s1);
    atomicAdd(&stats[Dx + c], q0);
    atomicAdd(&stats[Dx + c + 256], q1);
}

__global__ __launch_bounds__(256) void bn_norm(
    const float* __restrict__ t, const float* __restrict__ stats,
    const void* __restrict__ g32, const void* __restrict__ g16,
    const void* __restrict__ b32, const void* __restrict__ b16,
    float* __restrict__ h, const int* __restrict__ dtp)
{
    const int f32 = *dtp;
    size_t idx = (size_t)blockIdx.x * 256 + threadIdx.x;
    int c = idx & (Dx - 1);
    const float invM = 1.f / (float)TOK;
    float mu = stats[c] * invM;
    float var = stats[Dx + c] * invM - mu * mu;
    float v = (t[idx] - mu) * rsqrtf(var + EPSx) * ldsel(g32, g16, c, f32) + ldsel(b32, b16, c, f32);
    h[idx] = v;
}

// ---------------------------------------------------------------------------
__global__ __launch_bounds__(256) void out_h_kernel(const float* __restrict__ h, float* __restrict__ out)
{
    size_t idx = (size_t)blockIdx.x * 256 + threadIdx.x;
    out[idx] = h[idx];
}

__global__ __launch_bounds__(512) void out_mean_kernel(const float* __restrict__ h, float* __restrict__ out2)
{
    int b = blockIdx.x;
    int d = threadIdx.x;
    float s = 0.f;
    for (int n = 0; n < Nx; ++n) s += h[((size_t)b * Nx + n) * Dx + d];
    out2[b * Dx + d] = s * (1.f / (float)Nx);
}

// ---------------------------------------------------------------------------
extern "C" void kernel_launch(void* const* d_in, const int* in_sizes, int n_in,
                              void* d_out, int out_size, void* d_ws, size_t ws_size,
                              hipStream_t stream)
{
    const void* x   = d_in[0];
    const void* We  = d_in[1];
    const void* be  = d_in[2];
    const void* Wq  = d_in[3];
    const void* Wk  = d_in[4];
    const void* Wv  = d_in[5];
    const void* Wo  = d_in[6];
    const void* g1  = d_in[7];
    const void* b1  = d_in[8];
    const void* W1  = d_in[9];
    const void* bb1 = d_in[10];
    const void* W2  = d_in[11];
    const void* bb2 = d_in[12];
    const void* g2  = d_in[13];
    const void* b2  = d_in[14];

    const size_t szWqkv = (size_t)Hx * Dx * DKx;
    const size_t szWo   = (size_t)Hx * DKx * Dx;
    const size_t szW1   = (size_t)FFx * Dx;
    const size_t szW2   = (size_t)Dx * FFx;

    // workspace: h(32MB) | t(32MB) | stats/dtp | region(112MB)
    float* h     = (float*)d_ws;
    float* t     = h + (size_t)TOK * Dx;
    float* stats = t + (size_t)TOK * Dx;
    int*   dtp   = (int*)(stats + 2 * Dx);
    float* region = stats + 2 * Dx + 64;
    // attention-phase views: heads fp32 32MB, Q/K fp32 32MB each, V bf16 16MB
    const size_t QKN = (size_t)Hx * Bx * Nx * DKx;   // 8.4M elems
    float*  heads = region;
    float*  Qb    = heads + (size_t)TOK * Dx;
    float*  Kb    = Qb + QKN;
    __bf16* Vb    = (__bf16*)(Kb + QKN);
    // FF-phase view: ffbuf bf16 [TOK, FFx] = 64 MB (overlaps heads/Q)
    __bf16* ffbuf = (__bf16*)region;

    auto p32 = [](const void* p, size_t e) { return (const void*)((const float*)p + e); };
    auto p16 = [](const void* p, size_t e) { return (const void*)((const __hip_bfloat16*)p + e); };

    detect_kernel<<<1, 64, 0, stream>>>(x, dtp);
    embed_kernel<<<TOK * Dx / 256, 256, 0, stream>>>(x, We, be, h, dtp);

    const dim3 gQKV(24, TOK / 128);                   // (24, 128)
    const dim3 gWo(Dx / 64, TOK / 128);               // (8, 128)
    const dim3 gAttn(Nx / 64, Hx * Bx);               // (8, 256)
    const dim3 gFF1(FFx / 64, TOK / 128);             // (32, 128)
    const dim3 gFF2(Dx / 64, TOK / 128);              // (8, 128)
    for (int l = 0; l < 3; ++l) {
        const size_t eW = (size_t)l * szWqkv, eO = (size_t)l * szWo;
        const size_t e1 = (size_t)l * szW1,  e2 = (size_t)l * szW2;
        const size_t eD = (size_t)l * Dx,    eF = (size_t)l * FFx;

        qkv_mfma<<<gQKV, 256, 0, stream>>>(
            h, p32(Wq, eW), p16(Wq, eW), p32(Wk, eW), p16(Wk, eW),
            p32(Wv, eW), p16(Wv, eW), Qb, Kb, Vb, TOK, Dx, dtp);
        attn_kernel<<<gAttn, 256, 0, stream>>>(Qb, Kb, Vb, heads);

        // output projection + residual: t = h + heads @ Wo_flat
        gemm_mfma<2, 2, 0, 0><<<gWo, 256, 0, stream>>>(
            heads, p32(Wo, eO), p16(Wo, eO), nullptr, nullptr, h, t, TOK, Dx, Dx, dtp);

        hipMemsetAsync(stats, 0, 2 * Dx * sizeof(float), stream);
        bn_stats<<<256, 256, 0, stream>>>(t, stats);
        bn_norm<<<TOK * Dx / 256, 256, 0, stream>>>(
            t, stats, p32(g1, eD), p16(g1, eD), p32(b1, eD), p16(b1, eD), h, dtp);

        // FF: ffbuf bf16 [TOK, FFx]
        gemm_mfma<0, 1, 0, 1><<<gFF1, 256, 0, stream>>>(
            h, p32(W1, e1), p16(W1, e1), p32(bb1, eF), p16(bb1, eF), nullptr, ffbuf, TOK, FFx, Dx, dtp);
        gemm_mfma<0, 2, 1, 0><<<gFF2, 256, 0, stream>>>(
            ffbuf, p32(W2, e2), p16(W2, e2), p32(bb2, eD), p16(bb2, eD), h, t, TOK, Dx, FFx, dtp);

        hipMemsetAsync(stats, 0, 2 * Dx * sizeof(float), stream);
        bn_stats<<<256, 256, 0, stream>>>(t, stats);
        bn_norm<<<TOK * Dx / 256, 256, 0, stream>>>(
            t, stats, p32(g2, eD), p16(g2, eD), p32(b2, eD), p16(b2, eD), h, dtp);
    }

    out_h_kernel<<<TOK * Dx / 256, 256, 0, stream>>>(h, (float*)d_out);
    out_mean_kernel<<<Bx, Dx, 0, stream>>>(h, (float*)d_out + (size_t)TOK * Dx);
}